// Round 3
// baseline (2598.589 us; speedup 1.0000x reference)
//
#include <hip/hip_runtime.h>
#include <cmath>

#define BB 128
#define TT 256
#define DD 512
#define HH 256
#define G3 768   // 3*H
#define NWORK 256
#define NPAIR 128

typedef float v2f __attribute__((ext_vector_type(2)));
typedef unsigned long long ull;
// packed fp32 FMA (CDNA2+; this is how the 157.3 TF fp32 vector peak is reached)
#define PKFMA(acc, a, b) asm("v_pk_fma_f32 %0, %1, %2, %0" : "+v"(acc) : "v"(a), "v"(b))

// ---- GEMM: C[m,n] = bias[n] + sum_k A[m,k]*W[n,k]; A (M,K), W (N,K) ------
// inner product as v_pk_fma_f32: 32 pk-FMA + 8 broadcasts per k-step
// (vs 64 scalar v_fma) -> ~1.5x on the VALU-issue-bound path.
__global__ __launch_bounds__(256) void gemm_abt(
    const float* __restrict__ A, const float* __restrict__ W,
    const float* __restrict__ bias, float* __restrict__ C,
    int M, int N, int K)
{
  __shared__ float sA[16][132];
  __shared__ float sB[16][132];
  const int tid = threadIdx.x;
  const int row0 = blockIdx.y * 128, col0 = blockIdx.x * 128;
  const int tx = tid & 15, ty = tid >> 4;
  v2f acc2[8][4];
#pragma unroll
  for (int i = 0; i < 8; i++)
#pragma unroll
    for (int j = 0; j < 4; j++) acc2[i][j] = (v2f){0.f, 0.f};

  for (int k0 = 0; k0 < K; k0 += 16) {
    __syncthreads();
#pragma unroll
    for (int i = 0; i < 2; i++) {
      int q = tid + i * 256;
      int r = q >> 2, k4 = (q & 3) * 4;
      float4 av = *(const float4*)(A + (size_t)(row0 + r) * K + k0 + k4);
      sA[k4 + 0][r] = av.x; sA[k4 + 1][r] = av.y;
      sA[k4 + 2][r] = av.z; sA[k4 + 3][r] = av.w;
      float4 wv = make_float4(0.f, 0.f, 0.f, 0.f);
      if (col0 + r < N) wv = *(const float4*)(W + (size_t)(col0 + r) * K + k0 + k4);
      sB[k4 + 0][r] = wv.x; sB[k4 + 1][r] = wv.y;
      sB[k4 + 2][r] = wv.z; sB[k4 + 3][r] = wv.w;
    }
    __syncthreads();
#pragma unroll
    for (int k = 0; k < 16; k++) {
      float a0[8], b0[8];
      *(float4*)&a0[0] = *(const float4*)&sA[k][ty * 4];
      *(float4*)&a0[4] = *(const float4*)&sA[k][64 + ty * 4];
      *(float4*)&b0[0] = *(const float4*)&sB[k][tx * 4];
      *(float4*)&b0[4] = *(const float4*)&sB[k][64 + tx * 4];
      v2f ax[8];
#pragma unroll
      for (int i = 0; i < 8; i++) ax[i] = (v2f){a0[i], a0[i]};
      const v2f* b2v = (const v2f*)&b0[0];
#pragma unroll
      for (int i = 0; i < 8; i++)
#pragma unroll
        for (int j = 0; j < 4; j++) PKFMA(acc2[i][j], ax[i], b2v[j]);
    }
  }
  const float* accf = (const float*)acc2;   // accf[i*8 + col] == acc for b0[col]
#pragma unroll
  for (int i = 0; i < 8; i++) {
    int r = row0 + ((i < 4) ? (ty * 4 + i) : (64 + ty * 4 + i - 4));
#pragma unroll
    for (int jq = 0; jq < 2; jq++) {
      int c = col0 + jq * 64 + tx * 4;
      if (c < N) {
        float4 v;
        v.x = accf[i * 8 + jq * 4 + 0] + bias[c + 0];
        v.y = accf[i * 8 + jq * 4 + 1] + bias[c + 1];
        v.z = accf[i * 8 + jq * 4 + 2] + bias[c + 2];
        v.w = accf[i * 8 + jq * 4 + 3] + bias[c + 3];
        *(float4*)(C + (size_t)r * N + c) = v;
      }
    }
  }
}

// ---- LPT schedule: order_b[rank] = batch, ranked by length descending ----
__global__ void sched_kernel(const int* __restrict__ lengths,
                             int* __restrict__ order_b)
{
  const int b = threadIdx.x;
  if (b < BB) {
    const int L = lengths[b];
    int rank = 0;
    for (int j = 0; j < BB; j++) {
      const int Lj = lengths[j];
      rank += (Lj > L) || (Lj == L && j < b);
    }
    order_b[rank] = b;
  }
}

// ---- register-stationary GRU, STATIC same-XCD pairing -------------------
// 256 blocks, 1/CU (co-resident at this VGPR count). Pair = (bx, bx^8):
// bx and bx^8 differ only in bit 3, so they share bx%8 (round-robin XCD
// placement) AND bx>>5 (chunked placement) -> same-XCD under either policy.
// No registration/barrier (R2's racy scheduler is gone): a 2-word agent-
// scope handshake (single-writer, single-address => no ordering hazard)
// verifies the same-XCD assumption per pair; on mismatch the pair runs the
// proven agent-scope slow path. Fast path: h published with
// global_store_dwordx2 sc0 (write-through into the shared per-XCD L2) and
// polled with sc0 loads (L1-bypass, L2-served, ~300cy RT) instead of
// agent atomics that resolve past the non-coherent L2s (~1800cy RT).
// Poll escalates to an agent-scope load every 16th spin (deadlock-proof
// even if the placement assumption is wrong in some unmodeled way).
// Tasks: 256 (batch,dir) sorted by length desc; pair p statically takes
// tasks p and 255-p (folded: balanced sums, no mailbox/claim latency).
// Critical path = longest sequence (~256 steps) x per-step latency.
__global__ __launch_bounds__(256, 1) void gru_pair_kernel(
    const float* __restrict__ xg_f, const float* __restrict__ xg_b,
    const float* __restrict__ whh_f, const float* __restrict__ whh_b,
    const float* __restrict__ bhh_f, const float* __restrict__ bhh_b,
    const int* __restrict__ lengths, float* __restrict__ outp,
    ull* __restrict__ Hx,                  // [NPAIR][2 parity][HH] tagged
    int* __restrict__ hshk,                // [NPAIR][2] xcd+1 handshake
    const int* __restrict__ order_b,       // [BB] desc-length batch order
    int mode)                              // -1: fused (2 tasks/pair); 0/1: dir
{
  const int tid = threadIdx.x;
  const int bx = blockIdx.x;
  const int half = (bx >> 3) & 1;
  const int pid = ((bx >> 4) << 3) | (bx & 7);   // same for bx and bx^8
  __shared__ float h_s[HH];
  __shared__ int s_fast;

  // ---- per-pair handshake: verify same-XCD placement ----
  if (tid == 0) {
    unsigned x;
    asm volatile("s_getreg_b32 %0, hwreg(HW_REG_XCC_ID)" : "=s"(x));
    const int me = (int)(x & 7) + 1;
    __hip_atomic_store(&hshk[2 * pid + half], me,
                       __ATOMIC_RELAXED, __HIP_MEMORY_SCOPE_AGENT);
    int px;
    do {
      px = __hip_atomic_load(&hshk[2 * pid + (1 - half)],
                             __ATOMIC_RELAXED, __HIP_MEMORY_SCOPE_AGENT);
    } while (px == 0);
    s_fast = (px == me) ? 1 : 0;
  }
  __syncthreads();
  const int fast = s_fast;

  const int ul = tid >> 1, kc = tid & 1;
  const int u  = half * 128 + ul;
  const int po = (1 - half) * 128;
  const int koA = half * 128 + kc * 64;        // own-half k slice
  const int koB = (1 - half) * 128 + kc * 64;  // partner-half k slice
  ull* slotbase = Hx + (size_t)pid * (2 * HH);
  const int nslot = (mode < 0) ? 2 : 1;

  for (int slot = 0; slot < nslot; slot++) {
    int batch, dir;
    if (mode < 0) {
      const int q = (slot == 0) ? pid : (255 - pid);  // folded assignment
      batch = order_b[q >> 1]; dir = q & 1;
    } else {
      batch = order_b[pid]; dir = mode;
    }
    const unsigned base = (unsigned)(((slot + 1) << 10) | (dir << 9));

    const int len = lengths[batch];
    const float* xg   = dir ? xg_b  : xg_f;
    const float* w_hh = dir ? whh_b : whh_f;
    const float* bhh  = dir ? bhh_b : bhh_f;

    if (tid < HH) h_s[tid] = 0.f;

    // one-time (per task) weight load; asm barriers pin values in registers
    float4 wrA[16], wzA[16], wnA[16], wrB[16], wzB[16], wnB[16];
    {
      const float* pr = w_hh + (size_t)u * HH;
      const float* pz = pr + (size_t)HH * HH;
      const float* pn = pr + (size_t)2 * HH * HH;
#pragma unroll
      for (int i = 0; i < 16; i++) {
        wrA[i] = *(const float4*)(pr + koA + 4 * i);
        wzA[i] = *(const float4*)(pz + koA + 4 * i);
        wnA[i] = *(const float4*)(pn + koA + 4 * i);
        wrB[i] = *(const float4*)(pr + koB + 4 * i);
        wzB[i] = *(const float4*)(pz + koB + 4 * i);
        wnB[i] = *(const float4*)(pn + koB + 4 * i);
      }
#pragma unroll
      for (int i = 0; i < 16; i++) {
        asm volatile("" : "+v"(wrA[i].x), "+v"(wrA[i].y), "+v"(wrA[i].z), "+v"(wrA[i].w));
        asm volatile("" : "+v"(wzA[i].x), "+v"(wzA[i].y), "+v"(wzA[i].z), "+v"(wzA[i].w));
        asm volatile("" : "+v"(wnA[i].x), "+v"(wnA[i].y), "+v"(wnA[i].z), "+v"(wnA[i].w));
        asm volatile("" : "+v"(wrB[i].x), "+v"(wrB[i].y), "+v"(wrB[i].z), "+v"(wrB[i].w));
        asm volatile("" : "+v"(wzB[i].x), "+v"(wzB[i].y), "+v"(wzB[i].z), "+v"(wzB[i].w));
        asm volatile("" : "+v"(wnB[i].x), "+v"(wnB[i].y), "+v"(wnB[i].z), "+v"(wnB[i].w));
      }
    }
    const float br = bhh[u], bz = bhh[HH + u], bn = bhh[2 * HH + u];
    __syncthreads();

#define GATE_PHASE(KO, WR, WZ, WN)                                           \
    {                                                                        \
      const float* hp = h_s + (KO);                                          \
      float4 hb[8];                                                          \
      _Pragma("unroll")                                                      \
      for (int i2 = 0; i2 < 8; i2++) hb[i2] = *(const float4*)(hp + 4 * i2); \
      _Pragma("unroll")                                                      \
      for (int i2 = 0; i2 < 16; i2++) {                                      \
        float4 h4 = hb[i2 & 7];                                              \
        if (i2 < 8) hb[i2] = *(const float4*)(hp + 4 * (8 + i2));            \
        const v2f* h2  = (const v2f*)&h4;                                    \
        const v2f* w2r = (const v2f*)&WR[i2];                                \
        const v2f* w2z = (const v2f*)&WZ[i2];                                \
        const v2f* w2n = (const v2f*)&WN[i2];                                \
        PKFMA(ar2, h2[0], w2r[0]); PKFMA(ar2, h2[1], w2r[1]);                \
        PKFMA(az2, h2[0], w2z[0]); PKFMA(az2, h2[1], w2z[1]);                \
        PKFMA(an2, h2[0], w2n[0]); PKFMA(an2, h2[1], w2n[1]);                \
      }                                                                      \
    }

    // xg prefetch for t=0 (only kc==0 lanes consume it)
    int p = dir ? (len - 1) : 0;
    float xr_c = 0.f, xz_c = 0.f, xn_c = 0.f;
    if (kc == 0) {
      const float* x0 = xg + ((size_t)batch * TT + p) * G3;
      xr_c = x0[u]; xz_c = x0[HH + u]; xn_c = x0[2 * HH + u];
    }

    for (int t = 0; t < len; t++) {
      float xr_n = 0.f, xz_n = 0.f, xn_n = 0.f;
      if (kc == 0 && t + 1 < len) {
        const int pnx = dir ? (len - 2 - t) : (t + 1);
        const float* xp = xg + ((size_t)batch * TT + pnx) * G3;
        xr_n = xp[u]; xz_n = xp[HH + u]; xn_n = xp[2 * HH + u];
      }
      const float hold = h_s[u];
      v2f ar2 = {0.f, 0.f}, az2 = {0.f, 0.f}, an2 = {0.f, 0.f};

      // phase A: own-half k-slice (partner h still in flight -> off path)
      GATE_PHASE(koA, wrA, wzA, wnA);

      // poll partner h_{t-1} into LDS (parity buffer t&1, tag base|t)
      if (t > 0 && tid < 128) {
        const unsigned wtag = base | (unsigned)t;
        ull* sp = slotbase + (size_t)(t & 1) * HH + po + tid;
        ull v; int spin = 0;
        for (;;) {
          if (fast && (spin & 15) != 15) {
            asm volatile("global_load_dwordx2 %0, %1, off sc0\n\t"
                         "s_waitcnt vmcnt(0)"
                         : "=v"(v) : "v"(sp) : "memory");
          } else {
            v = __hip_atomic_load(sp, __ATOMIC_RELAXED, __HIP_MEMORY_SCOPE_AGENT);
          }
          if ((unsigned)(v >> 32) == wtag) break;
          spin++;
        }
        h_s[po + tid] = __uint_as_float((unsigned)v);
      }
      __syncthreads();

      // phase B: partner-half k-slice (critical path: recv -> publish)
      GATE_PHASE(koB, wrB, wzB, wnB);

      float ar = ar2.x + ar2.y, az = az2.x + az2.y, an = an2.x + an2.y;
      ar += __shfl_xor(ar, 1);
      az += __shfl_xor(az, 1);
      an += __shfl_xor(an, 1);

      if (kc == 0) {
        float r = 1.f / (1.f + expf(-(xr_c + ar + br)));
        float z = 1.f / (1.f + expf(-(xz_c + az + bz)));
        float n = tanhf(xn_c + r * (an + bn));
        float hn = (1.f - z) * n + z * hold;
        h_s[u] = hn;
        ull pk2 = ((ull)(base | (unsigned)(t + 1)) << 32) |
                  (ull)__float_as_uint(hn);
        ull* dst = slotbase + (size_t)((t + 1) & 1) * HH + u;
        if (fast) {
          asm volatile("global_store_dwordx2 %0, %1, off sc0"
                       :: "v"(dst), "v"(pk2) : "memory");
        } else {
          __hip_atomic_store(dst, pk2, __ATOMIC_RELAXED, __HIP_MEMORY_SCOPE_AGENT);
        }
        outp[((size_t)batch * TT + p) * (2 * HH) + dir * HH + u] = hn;
      }
      __syncthreads();
      xr_c = xr_n; xz_c = xz_n; xn_c = xn_n;
      p += dir ? -1 : 1;
    }
#undef GATE_PHASE
  }
}

// ------------- scores from hmid: relu, dot w2, +b2; mask t>=len ----------
__global__ __launch_bounds__(256) void score2_kernel(
    const float* __restrict__ hmid, const float* __restrict__ w2,
    const float* __restrict__ b2, const int* __restrict__ lengths,
    float* __restrict__ scores)
{
  const int wv = threadIdx.x >> 6, lane = threadIdx.x & 63;
  const int bt = blockIdx.x * 4 + wv;
  const int b = bt >> 8, t = bt & 255;
  float v = 0.f;
  if (t < lengths[b]) {
    float hv = fmaxf(hmid[(size_t)bt * 64 + lane], 0.f);
    v = hv * w2[lane];
#pragma unroll
    for (int o = 32; o > 0; o >>= 1) v += __shfl_down(v, o);
    v += b2[0];
  }
  if (lane == 0) scores[bt] = v;
}

// -------- softmax + top-3 + normalize + seq_feat, 1 block per batch ------
__global__ __launch_bounds__(256) void attn_kernel(
    const float* __restrict__ scores, const float* __restrict__ outp,
    const float* __restrict__ temp_ptr, const int* __restrict__ lengths,
    float* __restrict__ seq_feat)
{
  const int b = blockIdx.x;
  const int t = threadIdx.x;
  const int len = lengths[b];
  float temp = fminf(fmaxf(temp_ptr[0], 0.001f), 10.0f);
  __shared__ float red[256];
  __shared__ int redi[256];
  __shared__ float topv[3]; __shared__ int topi[3];
  __shared__ float vn[3]; __shared__ float vsum_s;
  const bool valid = t < len;
  float logit = valid ? scores[b * TT + t] / temp : -INFINITY;
  red[t] = logit; __syncthreads();
  for (int s = 128; s > 0; s >>= 1) {
    if (t < s) red[t] = fmaxf(red[t], red[t + s]);
    __syncthreads();
  }
  float mx = red[0]; __syncthreads();
  float e = valid ? expf(logit - mx) : 0.f;
  red[t] = e; __syncthreads();
  for (int s = 128; s > 0; s >>= 1) {
    if (t < s) red[t] += red[t + s];
    __syncthreads();
  }
  float sum = red[0]; __syncthreads();
  float myp = e / sum;
  for (int it = 0; it < 3; it++) {
    red[t] = myp; redi[t] = t; __syncthreads();
    for (int s = 128; s > 0; s >>= 1) {
      if (t < s) {
        float v2 = red[t + s]; int i2 = redi[t + s];
        if (v2 > red[t] || (v2 == red[t] && i2 < redi[t])) { red[t] = v2; redi[t] = i2; }
      }
      __syncthreads();
    }
    if (t == 0) { topv[it] = red[0]; topi[it] = redi[0]; }
    __syncthreads();
    if (t == topi[it]) myp = -1.f;
    __syncthreads();
  }
  if (t == 0) {
    int k_act = len < 3 ? len : 3;
    float vsum = 0.f;
    for (int jj = 0; jj < 3; jj++) if (jj < k_act) vsum += topv[jj];
    vsum_s = vsum;
    float denom = fmaxf(vsum, 1e-8f);
    for (int jj = 0; jj < 3; jj++) vn[jj] = (jj < k_act) ? topv[jj] / denom : 0.f;
  }
  __syncthreads();
  if (vsum_s > 1e-8f) {
    for (int hh = t; hh < 2 * HH; hh += 256) {
      float s = 0.f;
      for (int jj = 0; jj < 3; jj++)
        s += vn[jj] * outp[((size_t)b * TT + topi[jj]) * (2 * HH) + hh];
      seq_feat[b * 2 * HH + hh] = s;
    }
  } else {
    float inv = 1.f / ((float)len + 1e-8f);
    for (int hh = t; hh < 2 * HH; hh += 256) {
      float s = 0.f;
      for (int tt2 = 0; tt2 < len; tt2++)
        s += outp[((size_t)b * TT + tt2) * (2 * HH) + hh];
      seq_feat[b * 2 * HH + hh] = s * inv;
    }
  }
}

// ------------------- final heads: (B,11) then (B,10) ---------------------
__global__ __launch_bounds__(256) void head_kernel(
    const float* __restrict__ seq_feat,
    const float* __restrict__ w_tens, const float* __restrict__ b_tens,
    const float* __restrict__ w_ones, const float* __restrict__ b_ones,
    float* __restrict__ d_out)
{
  const int b = blockIdx.x;
  const int lane = threadIdx.x & 63, wv = threadIdx.x >> 6;
  const float* sf = seq_feat + (size_t)b * 2 * HH;
  for (int o = wv; o < 21; o += 4) {
    const float* wr = (o < 11) ? (w_tens + (size_t)o * 2 * HH)
                               : (w_ones + (size_t)(o - 11) * 2 * HH);
    float s = 0.f;
    for (int e2 = lane; e2 < 2 * HH; e2 += 64) s += sf[e2] * wr[e2];
#pragma unroll
    for (int off2 = 32; off2 > 0; off2 >>= 1) s += __shfl_down(s, off2);
    if (lane == 0) {
      if (o < 11) d_out[b * 11 + o] = s + b_tens[o];
      else d_out[BB * 11 + b * 10 + (o - 11)] = s + b_ones[o - 11];
    }
  }
}

extern "C" void kernel_launch(void* const* d_in, const int* in_sizes, int n_in,
                              void* d_out, int out_size, void* d_ws, size_t ws_size,
                              hipStream_t stream)
{
  const float* feats       = (const float*)d_in[0];
  const int*   lengths     = (const int*)d_in[1];
  const float* temperature = (const float*)d_in[2];
  const float* w_ih_f = (const float*)d_in[3];
  const float* w_hh_f = (const float*)d_in[4];
  const float* b_ih_f = (const float*)d_in[5];
  const float* b_hh_f = (const float*)d_in[6];
  const float* w_ih_b = (const float*)d_in[7];
  const float* w_hh_b = (const float*)d_in[8];
  const float* b_ih_b = (const float*)d_in[9];
  const float* b_hh_b = (const float*)d_in[10];
  const float* w1 = (const float*)d_in[11];
  const float* b1 = (const float*)d_in[12];
  const float* w2 = (const float*)d_in[13];
  const float* b2 = (const float*)d_in[14];
  const float* w_tens = (const float*)d_in[15];
  const float* b_tens = (const float*)d_in[16];
  const float* w_ones = (const float*)d_in[17];
  const float* b_ones = (const float*)d_in[18];
  float* out = (float*)d_out;

  const size_t xg_sz   = (size_t)BB * TT * G3 * 4;        // 100.7 MB
  const size_t outp_sz = (size_t)BB * TT * 2 * HH * 4;    // 67.1 MB
  const size_t hx_sz   = (size_t)NPAIR * 2 * HH * 8;      // 512 KB
  const size_t hsk_sz  = 4096;                            // handshake words
  const size_t ctl_sz  = hx_sz + hsk_sz;                  // memset region
  const size_t ord_sz  = 512;
  char* ws = (char*)d_ws;

  const size_t fused_need = 2 * xg_sz + outp_sz + ctl_sz + ord_sz;

  if (ws_size >= fused_need) {
    // ---------- fused path: both xg buffers live, one 256-worker GRU -----
    float* xg_f = (float*)ws;
    float* xg_b = (float*)(ws + xg_sz);
    float* outp = (float*)(ws + 2 * xg_sz);
    char*  ctl  = ws + 2 * xg_sz + outp_sz;
    ull*   Hx      = (ull*)ctl;
    int*   hshk    = (int*)(ctl + hx_sz);
    int*   order_b = (int*)(ctl + ctl_sz);
    float* hmid     = xg_f;                  // aliases (xg dead after GRU)
    float* scores   = xg_f + (size_t)BB * TT * 64;
    float* seq_feat = scores + (size_t)BB * TT;

    hipMemsetAsync(ctl, 0, ctl_sz, stream);
    sched_kernel<<<1, 128, 0, stream>>>(lengths, order_b);
    gemm_abt<<<dim3(6, 256), 256, 0, stream>>>(feats, w_ih_f, b_ih_f, xg_f, BB * TT, G3, DD);
    gemm_abt<<<dim3(6, 256), 256, 0, stream>>>(feats, w_ih_b, b_ih_b, xg_b, BB * TT, G3, DD);
    gru_pair_kernel<<<NWORK, 256, 0, stream>>>(
        xg_f, xg_b, w_hh_f, w_hh_b, b_hh_f, b_hh_b, lengths, outp, Hx,
        hshk, order_b, -1);
    gemm_abt<<<dim3(1, 256), 256, 0, stream>>>(outp, w1, b1, hmid, BB * TT, 64, 2 * HH);
    score2_kernel<<<BB * TT / 4, 256, 0, stream>>>(hmid, w2, b2, lengths, scores);
    attn_kernel<<<BB, 256, 0, stream>>>(scores, outp, temperature, lengths, seq_feat);
    head_kernel<<<BB, 256, 0, stream>>>(seq_feat, w_tens, b_tens, w_ones, b_ones, out);
  } else {
    // ---------- fallback: xg shared, two serial GRU launches -------------
    float* xg   = (float*)ws;
    float* outp = (float*)(ws + xg_sz);
    char*  ctl  = ws + xg_sz + outp_sz;
    ull*   Hx      = (ull*)ctl;
    int*   hshk    = (int*)(ctl + hx_sz);
    int*   order_b = (int*)(ctl + ctl_sz);
    float* hmid     = xg;
    float* scores   = xg + (size_t)BB * TT * 64;
    float* seq_feat = scores + (size_t)BB * TT;

    hipMemsetAsync(ctl, 0, ctl_sz, stream);
    sched_kernel<<<1, 128, 0, stream>>>(lengths, order_b);
    gemm_abt<<<dim3(6, 256), 256, 0, stream>>>(feats, w_ih_f, b_ih_f, xg, BB * TT, G3, DD);
    gru_pair_kernel<<<NWORK, 256, 0, stream>>>(
        xg, xg, w_hh_f, w_hh_b, b_hh_f, b_hh_b, lengths, outp, Hx,
        hshk, order_b, 0);
    hipMemsetAsync(ctl, 0, ctl_sz, stream);
    gemm_abt<<<dim3(6, 256), 256, 0, stream>>>(feats, w_ih_b, b_ih_b, xg, BB * TT, G3, DD);
    gru_pair_kernel<<<NWORK, 256, 0, stream>>>(
        xg, xg, w_hh_f, w_hh_b, b_hh_f, b_hh_b, lengths, outp, Hx,
        hshk, order_b, 1);
    gemm_abt<<<dim3(1, 256), 256, 0, stream>>>(outp, w1, b1, hmid, BB * TT, 64, 2 * HH);
    score2_kernel<<<BB * TT / 4, 256, 0, stream>>>(hmid, w2, b2, lengths, scores);
    attn_kernel<<<BB, 256, 0, stream>>>(scores, outp, temperature, lengths, seq_feat);
    head_kernel<<<BB, 256, 0, stream>>>(seq_feat, w_tens, b_tens, w_ones, b_ones, out);
  }
}

// Round 4
// 2016.729 us; speedup vs baseline: 1.2885x; 1.2885x over previous
//
#include <hip/hip_runtime.h>
#include <cmath>

#define BB 128
#define TT 256
#define DD 512
#define HH 256
#define G3 768   // 3*H

typedef float v2f __attribute__((ext_vector_type(2)));
typedef float f32x4 __attribute__((ext_vector_type(4)));
typedef short s16x8 __attribute__((ext_vector_type(8)));
typedef unsigned long long ull;
// packed fp32 FMA (CDNA2+)
#define PKFMA(acc, a, b) asm("v_pk_fma_f32 %0, %1, %2, %0" : "+v"(acc) : "v"(a), "v"(b))

// RNE float -> (hi bf16, lo bf16) split: x ~= hi + lo, |err| ~ 2^-17 |x|
__device__ __forceinline__ void split_bf16(float x, unsigned short& h, unsigned short& l)
{
  unsigned u = __float_as_uint(x);
  unsigned hr = u + 0x7fffu + ((u >> 16) & 1u);
  h = (unsigned short)(hr >> 16);
  float hf = __uint_as_float((unsigned)h << 16);
  float lo = x - hf;
  unsigned u2 = __float_as_uint(lo);
  unsigned lr2 = u2 + 0x7fffu + ((u2 >> 16) & 1u);
  l = (unsigned short)(lr2 >> 16);
}

// ---- MFMA split-bf16 GEMM: C[m,n] = bias[n] + sum_k A[m,k]*W[n,k] -------
// A (M,K) fp32, W (N,K) fp32. Each fp32 split to hi+lo bf16; product via
// 3 MFMAs (hi*hi + hi*lo + lo*hi), fp32 accumulate -> ~1e-5 relative error.
// 128x128 tile, 4 waves (2x2), each wave 64x64 = 4x4 fragments 16x16x32.
// Frag layouts (guide, m89-verified): A-op lane l: row=l&15, k=(l>>4)*8+j;
// B-op lane l: col=l&15, k=(l>>4)*8+j; C/D: col=l&15, row=(l>>4)*4+reg.
// Both operands read 8 contiguous K elems per lane -> no transpose needed.
__global__ __launch_bounds__(256) void gemm_mfma(
    const float* __restrict__ A, const float* __restrict__ W,
    const float* __restrict__ bias, float* __restrict__ C,
    int M, int N, int K)
{
  // uint = 2 bf16 (k-pair); row stride 20 uints = 80B (16B-aligned, de-conflicted)
  __shared__ unsigned aH[128][20], aL[128][20], bH[128][20], bL[128][20];
  const int tid = threadIdx.x;
  const int row0 = blockIdx.y * 128, col0 = blockIdx.x * 128;
  const int wid = tid >> 6, lane = tid & 63;
  const int wm = wid >> 1, wn = wid & 1;
  const int lr = lane & 15, kq = lane >> 4;
  const int sr = tid >> 1, sk = (tid & 1) * 16;   // staging: row sr, k-half sk

  f32x4 acc[4][4];
#pragma unroll
  for (int i = 0; i < 4; i++)
#pragma unroll
    for (int j = 0; j < 4; j++) acc[i][j] = (f32x4){0.f, 0.f, 0.f, 0.f};

  const float* ap = A + (size_t)(row0 + sr) * K + sk;
  const float* wp = W + (size_t)(col0 + sr) * K + sk;
  const bool wok = (col0 + sr) < N;
  float4 av[4], wv4[4];
#pragma unroll
  for (int i = 0; i < 4; i++) {
    av[i] = *(const float4*)(ap + 4 * i);
    wv4[i] = wok ? *(const float4*)(wp + 4 * i) : make_float4(0.f, 0.f, 0.f, 0.f);
  }

  for (int k0 = 0; k0 < K; k0 += 32) {
    __syncthreads();               // previous compute done reading LDS
    // convert current chunk regs -> LDS (hi/lo planes)
#pragma unroll
    for (int i = 0; i < 4; i++) {
      const float* fa = (const float*)&av[i];
      const float* fw = (const float*)&wv4[i];
#pragma unroll
      for (int j2 = 0; j2 < 2; j2++) {
        unsigned short h0, l0, h1, l1;
        const int col = (sk >> 1) + i * 2 + j2;
        split_bf16(fa[2 * j2], h0, l0);
        split_bf16(fa[2 * j2 + 1], h1, l1);
        aH[sr][col] = (unsigned)h0 | ((unsigned)h1 << 16);
        aL[sr][col] = (unsigned)l0 | ((unsigned)l1 << 16);
        split_bf16(fw[2 * j2], h0, l0);
        split_bf16(fw[2 * j2 + 1], h1, l1);
        bH[sr][col] = (unsigned)h0 | ((unsigned)h1 << 16);
        bL[sr][col] = (unsigned)l0 | ((unsigned)l1 << 16);
      }
    }
    __syncthreads();
    // register-prefetch next chunk (latency hides under MFMA)
    if (k0 + 32 < K) {
#pragma unroll
      for (int i = 0; i < 4; i++) {
        av[i] = *(const float4*)(ap + k0 + 32 + 4 * i);
        wv4[i] = wok ? *(const float4*)(wp + k0 + 32 + 4 * i)
                     : make_float4(0.f, 0.f, 0.f, 0.f);
      }
    }
    // fragments
    s16x8 ah[4], al4[4], bh[4], bl4[4];
#pragma unroll
    for (int f = 0; f < 4; f++) {
      const int ra = wm * 64 + f * 16 + lr;
      const int rb = wn * 64 + f * 16 + lr;
      ah[f]  = *(const s16x8*)((const short*)&aH[ra][0] + kq * 8);
      al4[f] = *(const s16x8*)((const short*)&aL[ra][0] + kq * 8);
      bh[f]  = *(const s16x8*)((const short*)&bH[rb][0] + kq * 8);
      bl4[f] = *(const s16x8*)((const short*)&bL[rb][0] + kq * 8);
    }
#pragma unroll
    for (int mf = 0; mf < 4; mf++)
#pragma unroll
      for (int nf = 0; nf < 4; nf++) {
        acc[mf][nf] = __builtin_amdgcn_mfma_f32_16x16x32_bf16(ah[mf],  bh[nf],  acc[mf][nf], 0, 0, 0);
        acc[mf][nf] = __builtin_amdgcn_mfma_f32_16x16x32_bf16(ah[mf],  bl4[nf], acc[mf][nf], 0, 0, 0);
        acc[mf][nf] = __builtin_amdgcn_mfma_f32_16x16x32_bf16(al4[mf], bh[nf],  acc[mf][nf], 0, 0, 0);
      }
  }
  // epilogue: C/D layout col=lane&15, row=(lane>>4)*4+reg
#pragma unroll
  for (int mf = 0; mf < 4; mf++)
#pragma unroll
    for (int nf = 0; nf < 4; nf++) {
      const int c = col0 + wn * 64 + nf * 16 + lr;
      if (c < N) {
        const float bsv = bias[c];
#pragma unroll
        for (int i = 0; i < 4; i++) {
          const int r = row0 + wm * 64 + mf * 16 + kq * 4 + i;
          C[(size_t)r * N + c] = acc[mf][nf][i] + bsv;
        }
      }
    }
}

// ---- LPT schedule: order_b[rank] = batch, ranked by length descending ----
__global__ void sched_kernel(const int* __restrict__ lengths,
                             int* __restrict__ order_b)
{
  const int b = threadIdx.x;
  if (b < BB) {
    const int L = lengths[b];
    int rank = 0;
    for (int j = 0; j < BB; j++) {
      const int Lj = lengths[j];
      rank += (Lj > L) || (Lj == L && j < b);
    }
    order_b[rank] = b;
  }
}

// ---- interleaved dual-task GRU, static pairs (bx, bx^1) -----------------
// 256 blocks, 1/CU. Pair pid=bx>>1 handles TWO same-direction tasks X,Y
// (sorted-adjacent batches -> similar length, SAME register weights).
// Per period: poll partner h_X(t-1),h_Y(t-1) (one combined RT) -> barrier
// -> compute X (FMA+act), publish -> compute Y, publish. The partner's
// publish has a full period (~1400cy of FMA) of slack before consumption,
// hiding the ~1us agent-scope visibility latency that dominated R1/R3.
// Exchange = R1's PROVEN relaxed agent-scope tagged 64-bit atomics (the R3
// sc0/L2 experiment is reverted: counters showed it engaged and was slower).
// LDS h double-buffered by parity (one barrier per period). Sticky bailout
// (4096 spins) turns any pathological stall into a fast wrong-answer
// instead of a hang. Tags = t+1, slots zeroed per launch; parity overwrite
// is race-free by the R1 lockstep argument.
__global__ __launch_bounds__(256, 1) void gru_duo_kernel(
    const float* __restrict__ xg_f, const float* __restrict__ xg_b,
    const float* __restrict__ whh_f, const float* __restrict__ whh_b,
    const float* __restrict__ bhh_f, const float* __restrict__ bhh_b,
    const int* __restrict__ lengths, float* __restrict__ outp,
    ull* __restrict__ Hx,                  // [NPAIR=128][2 task][2 parity][HH]
    const int* __restrict__ order_b,       // [BB] desc-length batch order
    int mode)                              // -1 fused; 0/1 single-dir fallback
{
  const int tid = threadIdx.x;
  const int bx = blockIdx.x;
  const int pid = bx >> 1, half = bx & 1;

  int dir, batchX, batchY, lenX, lenY;
  if (mode < 0) {
    dir = pid >> 6;                        // pairs 0-63 fwd, 64-127 bwd
    const int q = pid & 63;
    batchX = order_b[2 * q]; batchY = order_b[2 * q + 1];
    lenX = lengths[batchX];  lenY = lengths[batchY];   // lenX >= lenY
  } else {
    dir = mode; batchX = order_b[pid]; batchY = 0;
    lenX = lengths[batchX];  lenY = 0;
  }

  const int kc = tid & 1, ul = tid >> 1;
  const int u  = half * 128 + ul;
  const int po = (1 - half) * 128;
  const int k0 = kc * 128;
  const float* xg   = dir ? xg_b  : xg_f;
  const float* w_hh = dir ? whh_b : whh_f;
  const float* bhh  = dir ? bhh_b : bhh_f;
  ull* slotX = Hx + (size_t)(pid * 2 + 0) * (2 * HH);
  ull* slotY = Hx + (size_t)(pid * 2 + 1) * (2 * HH);

  __shared__ float hX[2][HH];
  __shared__ float hY[2][HH];
  __shared__ int s_dead;
  hX[0][tid] = 0.f; hY[0][tid] = 0.f;
  if (tid == 0) s_dead = 0;

  // one-time weight load (shared by both tasks: same direction)
  float4 wr[32], wz[32], wn[32];
  {
    const float* pr = w_hh + (size_t)u * HH + k0;
    const float* pz = w_hh + (size_t)(HH + u) * HH + k0;
    const float* pn = w_hh + (size_t)(2 * HH + u) * HH + k0;
#pragma unroll
    for (int i = 0; i < 32; i++) {
      wr[i] = *(const float4*)(pr + 4 * i);
      wz[i] = *(const float4*)(pz + 4 * i);
      wn[i] = *(const float4*)(pn + 4 * i);
    }
#pragma unroll
    for (int i = 0; i < 32; i++) {
      asm volatile("" : "+v"(wr[i].x), "+v"(wr[i].y), "+v"(wr[i].z), "+v"(wr[i].w));
      asm volatile("" : "+v"(wz[i].x), "+v"(wz[i].y), "+v"(wz[i].z), "+v"(wz[i].w));
      asm volatile("" : "+v"(wn[i].x), "+v"(wn[i].y), "+v"(wn[i].z), "+v"(wn[i].w));
    }
  }
  const float br = bhh[u], bz = bhh[HH + u], bn = bhh[2 * HH + u];
  __syncthreads();

#define GATE(HB, AR, AZ, AN)                                                 \
    {                                                                        \
      const float4* hp4 = (const float4*)((HB) + k0);                        \
      float4 hb[8];                                                          \
      _Pragma("unroll")                                                      \
      for (int i2 = 0; i2 < 8; i2++) hb[i2] = hp4[i2];                       \
      _Pragma("unroll")                                                      \
      for (int i2 = 0; i2 < 32; i2++) {                                      \
        float4 h4 = hb[i2 & 7];                                              \
        if (i2 < 24) hb[i2 & 7] = hp4[i2 + 8];                               \
        const v2f* h2  = (const v2f*)&h4;                                    \
        const v2f* w2r = (const v2f*)&wr[i2];                                \
        const v2f* w2z = (const v2f*)&wz[i2];                                \
        const v2f* w2n = (const v2f*)&wn[i2];                                \
        PKFMA(AR, h2[0], w2r[0]); PKFMA(AR, h2[1], w2r[1]);                  \
        PKFMA(AZ, h2[0], w2z[0]); PKFMA(AZ, h2[1], w2z[1]);                  \
        PKFMA(AN, h2[0], w2n[0]); PKFMA(AN, h2[1], w2n[1]);                  \
      }                                                                      \
    }

  // xg prefetch for t=0 (kc==0 lanes consume)
  int pX = dir ? (lenX - 1) : 0;
  int pY = dir ? (lenY - 1) : 0;
  float xrX = 0.f, xzX = 0.f, xnX = 0.f, xrY = 0.f, xzY = 0.f, xnY = 0.f;
  if (kc == 0) {
    const float* x0 = xg + ((size_t)batchX * TT + pX) * G3;
    xrX = x0[u]; xzX = x0[HH + u]; xnX = x0[2 * HH + u];
    if (lenY > 0) {
      const float* y0 = xg + ((size_t)batchY * TT + pY) * G3;
      xrY = y0[u]; xzY = y0[HH + u]; xnY = y0[2 * HH + u];
    }
  }

  for (int t = 0; t < lenX; t++) {
    const bool doY = t < lenY;
    // ---- combined poll of partner halves (one round trip for X and Y) ----
    if (t > 0 && tid < 128 && !s_dead) {
      const unsigned tg = (unsigned)t;
      ull* spx = slotX + (size_t)(t & 1) * HH + po + tid;
      ull* spy = slotY + (size_t)(t & 1) * HH + po + tid;
      ull vx, vy = 0;
      int gd = 0;
      for (;;) {
        vx = __hip_atomic_load(spx, __ATOMIC_RELAXED, __HIP_MEMORY_SCOPE_AGENT);
        if (doY) vy = __hip_atomic_load(spy, __ATOMIC_RELAXED, __HIP_MEMORY_SCOPE_AGENT);
        if ((unsigned)(vx >> 32) == tg && (!doY || (unsigned)(vy >> 32) == tg)) break;
        if (++gd > 4096) { s_dead = 1; break; }   // sticky bailout (anti-hang)
      }
      hX[t & 1][po + tid] = __uint_as_float((unsigned)vx);
      if (doY) hY[t & 1][po + tid] = __uint_as_float((unsigned)vy);
    }
    __syncthreads();

    // next-step xg prefetch (hidden under both FMA blocks)
    float nrX = 0.f, nzX = 0.f, nnX = 0.f, nrY = 0.f, nzY = 0.f, nnY = 0.f;
    if (kc == 0) {
      if (t + 1 < lenX) {
        const int pn2 = dir ? (lenX - 2 - t) : (t + 1);
        const float* xp = xg + ((size_t)batchX * TT + pn2) * G3;
        nrX = xp[u]; nzX = xp[HH + u]; nnX = xp[2 * HH + u];
      }
      if (t + 1 < lenY) {
        const int pn2 = dir ? (lenY - 2 - t) : (t + 1);
        const float* yp = xg + ((size_t)batchY * TT + pn2) * G3;
        nrY = yp[u]; nzY = yp[HH + u]; nnY = yp[2 * HH + u];
      }
    }

    // ---- task X ----
    {
      const float hold = hX[t & 1][u];
      v2f ar2 = {0.f, 0.f}, az2 = {0.f, 0.f}, an2 = {0.f, 0.f};
      GATE(hX[t & 1], ar2, az2, an2);
      float ar = ar2.x + ar2.y, az = az2.x + az2.y, an = an2.x + an2.y;
      ar += __shfl_xor(ar, 1); az += __shfl_xor(az, 1); an += __shfl_xor(an, 1);
      if (kc == 0) {
        float r = 1.f / (1.f + expf(-(xrX + ar + br)));
        float z = 1.f / (1.f + expf(-(xzX + az + bz)));
        float n = tanhf(xnX + r * (an + bn));
        float hn = (1.f - z) * n + z * hold;
        hX[(t + 1) & 1][u] = hn;
        ull pk = ((ull)(unsigned)(t + 1) << 32) | (ull)__float_as_uint(hn);
        __hip_atomic_store(slotX + (size_t)((t + 1) & 1) * HH + u, pk,
                           __ATOMIC_RELAXED, __HIP_MEMORY_SCOPE_AGENT);
        outp[((size_t)batchX * TT + pX) * (2 * HH) + dir * HH + u] = hn;
      }
    }
    // ---- task Y ----
    if (doY) {
      const float hold = hY[t & 1][u];
      v2f ar2 = {0.f, 0.f}, az2 = {0.f, 0.f}, an2 = {0.f, 0.f};
      GATE(hY[t & 1], ar2, az2, an2);
      float ar = ar2.x + ar2.y, az = az2.x + az2.y, an = an2.x + an2.y;
      ar += __shfl_xor(ar, 1); az += __shfl_xor(az, 1); an += __shfl_xor(an, 1);
      if (kc == 0) {
        float r = 1.f / (1.f + expf(-(xrY + ar + br)));
        float z = 1.f / (1.f + expf(-(xzY + az + bz)));
        float n = tanhf(xnY + r * (an + bn));
        float hn = (1.f - z) * n + z * hold;
        hY[(t + 1) & 1][u] = hn;
        ull pk = ((ull)(unsigned)(t + 1) << 32) | (ull)__float_as_uint(hn);
        __hip_atomic_store(slotY + (size_t)((t + 1) & 1) * HH + u, pk,
                           __ATOMIC_RELAXED, __HIP_MEMORY_SCOPE_AGENT);
        outp[((size_t)batchY * TT + pY) * (2 * HH) + dir * HH + u] = hn;
      }
    }
    pX += dir ? -1 : 1;
    pY += dir ? -1 : 1;
    xrX = nrX; xzX = nzX; xnX = nnX;
    xrY = nrY; xzY = nzY; xnY = nnY;
  }
#undef GATE
}

// ------------- scores from hmid: relu, dot w2, +b2; mask t>=len ----------
__global__ __launch_bounds__(256) void score2_kernel(
    const float* __restrict__ hmid, const float* __restrict__ w2,
    const float* __restrict__ b2, const int* __restrict__ lengths,
    float* __restrict__ scores)
{
  const int wv = threadIdx.x >> 6, lane = threadIdx.x & 63;
  const int bt = blockIdx.x * 4 + wv;
  const int b = bt >> 8, t = bt & 255;
  float v = 0.f;
  if (t < lengths[b]) {
    float hv = fmaxf(hmid[(size_t)bt * 64 + lane], 0.f);
    v = hv * w2[lane];
#pragma unroll
    for (int o = 32; o > 0; o >>= 1) v += __shfl_down(v, o);
    v += b2[0];
  }
  if (lane == 0) scores[bt] = v;
}

// -------- softmax + top-3 + normalize + seq_feat, 1 block per batch ------
__global__ __launch_bounds__(256) void attn_kernel(
    const float* __restrict__ scores, const float* __restrict__ outp,
    const float* __restrict__ temp_ptr, const int* __restrict__ lengths,
    float* __restrict__ seq_feat)
{
  const int b = blockIdx.x;
  const int t = threadIdx.x;
  const int len = lengths[b];
  float temp = fminf(fmaxf(temp_ptr[0], 0.001f), 10.0f);
  __shared__ float red[256];
  __shared__ int redi[256];
  __shared__ float topv[3]; __shared__ int topi[3];
  __shared__ float vn[3]; __shared__ float vsum_s;
  const bool valid = t < len;
  float logit = valid ? scores[b * TT + t] / temp : -INFINITY;
  red[t] = logit; __syncthreads();
  for (int s = 128; s > 0; s >>= 1) {
    if (t < s) red[t] = fmaxf(red[t], red[t + s]);
    __syncthreads();
  }
  float mx = red[0]; __syncthreads();
  float e = valid ? expf(logit - mx) : 0.f;
  red[t] = e; __syncthreads();
  for (int s = 128; s > 0; s >>= 1) {
    if (t < s) red[t] += red[t + s];
    __syncthreads();
  }
  float sum = red[0]; __syncthreads();
  float myp = e / sum;
  for (int it = 0; it < 3; it++) {
    red[t] = myp; redi[t] = t; __syncthreads();
    for (int s = 128; s > 0; s >>= 1) {
      if (t < s) {
        float v2 = red[t + s]; int i2 = redi[t + s];
        if (v2 > red[t] || (v2 == red[t] && i2 < redi[t])) { red[t] = v2; redi[t] = i2; }
      }
      __syncthreads();
    }
    if (t == 0) { topv[it] = red[0]; topi[it] = redi[0]; }
    __syncthreads();
    if (t == topi[it]) myp = -1.f;
    __syncthreads();
  }
  if (t == 0) {
    int k_act = len < 3 ? len : 3;
    float vsum = 0.f;
    for (int jj = 0; jj < 3; jj++) if (jj < k_act) vsum += topv[jj];
    vsum_s = vsum;
    float denom = fmaxf(vsum, 1e-8f);
    for (int jj = 0; jj < 3; jj++) vn[jj] = (jj < k_act) ? topv[jj] / denom : 0.f;
  }
  __syncthreads();
  if (vsum_s > 1e-8f) {
    for (int hh = t; hh < 2 * HH; hh += 256) {
      float s = 0.f;
      for (int jj = 0; jj < 3; jj++)
        s += vn[jj] * outp[((size_t)b * TT + topi[jj]) * (2 * HH) + hh];
      seq_feat[b * 2 * HH + hh] = s;
    }
  } else {
    float inv = 1.f / ((float)len + 1e-8f);
    for (int hh = t; hh < 2 * HH; hh += 256) {
      float s = 0.f;
      for (int tt2 = 0; tt2 < len; tt2++)
        s += outp[((size_t)b * TT + tt2) * (2 * HH) + hh];
      seq_feat[b * 2 * HH + hh] = s * inv;
    }
  }
}

// ------------------- final heads: (B,11) then (B,10) ---------------------
__global__ __launch_bounds__(256) void head_kernel(
    const float* __restrict__ seq_feat,
    const float* __restrict__ w_tens, const float* __restrict__ b_tens,
    const float* __restrict__ w_ones, const float* __restrict__ b_ones,
    float* __restrict__ d_out)
{
  const int b = blockIdx.x;
  const int lane = threadIdx.x & 63, wv = threadIdx.x >> 6;
  const float* sf = seq_feat + (size_t)b * 2 * HH;
  for (int o = wv; o < 21; o += 4) {
    const float* wr = (o < 11) ? (w_tens + (size_t)o * 2 * HH)
                               : (w_ones + (size_t)(o - 11) * 2 * HH);
    float s = 0.f;
    for (int e2 = lane; e2 < 2 * HH; e2 += 64) s += sf[e2] * wr[e2];
#pragma unroll
    for (int off2 = 32; off2 > 0; off2 >>= 1) s += __shfl_down(s, off2);
    if (lane == 0) {
      if (o < 11) d_out[b * 11 + o] = s + b_tens[o];
      else d_out[BB * 11 + b * 10 + (o - 11)] = s + b_ones[o - 11];
    }
  }
}

extern "C" void kernel_launch(void* const* d_in, const int* in_sizes, int n_in,
                              void* d_out, int out_size, void* d_ws, size_t ws_size,
                              hipStream_t stream)
{
  const float* feats       = (const float*)d_in[0];
  const int*   lengths     = (const int*)d_in[1];
  const float* temperature = (const float*)d_in[2];
  const float* w_ih_f = (const float*)d_in[3];
  const float* w_hh_f = (const float*)d_in[4];
  const float* b_ih_f = (const float*)d_in[5];
  const float* b_hh_f = (const float*)d_in[6];
  const float* w_ih_b = (const float*)d_in[7];
  const float* w_hh_b = (const float*)d_in[8];
  const float* b_ih_b = (const float*)d_in[9];
  const float* b_hh_b = (const float*)d_in[10];
  const float* w1 = (const float*)d_in[11];
  const float* b1 = (const float*)d_in[12];
  const float* w2 = (const float*)d_in[13];
  const float* b2 = (const float*)d_in[14];
  const float* w_tens = (const float*)d_in[15];
  const float* b_tens = (const float*)d_in[16];
  const float* w_ones = (const float*)d_in[17];
  const float* b_ones = (const float*)d_in[18];
  float* out = (float*)d_out;

  const size_t xg_sz   = (size_t)BB * TT * G3 * 4;        // 100.7 MB
  const size_t outp_sz = (size_t)BB * TT * 2 * HH * 4;    // 67.1 MB
  const size_t hx_sz   = (size_t)128 * 2 * 2 * HH * 8;    // 1 MiB tagged slots
  const size_t ord_sz  = 512;
  char* ws = (char*)d_ws;

  const size_t fused_need = 2 * xg_sz + outp_sz + hx_sz + ord_sz;

  if (ws_size >= fused_need) {
    // ---------- fused path: both xg buffers live, one duo-GRU launch -----
    float* xg_f = (float*)ws;
    float* xg_b = (float*)(ws + xg_sz);
    float* outp = (float*)(ws + 2 * xg_sz);
    ull*   Hx      = (ull*)(ws + 2 * xg_sz + outp_sz);
    int*   order_b = (int*)(ws + 2 * xg_sz + outp_sz + hx_sz);
    float* hmid     = xg_f;                  // aliases (xg dead after GRU)
    float* scores   = xg_f + (size_t)BB * TT * 64;
    float* seq_feat = scores + (size_t)BB * TT;

    hipMemsetAsync(Hx, 0, hx_sz, stream);
    sched_kernel<<<1, 128, 0, stream>>>(lengths, order_b);
    gemm_mfma<<<dim3(6, 256), 256, 0, stream>>>(feats, w_ih_f, b_ih_f, xg_f, BB * TT, G3, DD);
    gemm_mfma<<<dim3(6, 256), 256, 0, stream>>>(feats, w_ih_b, b_ih_b, xg_b, BB * TT, G3, DD);
    gru_duo_kernel<<<256, 256, 0, stream>>>(
        xg_f, xg_b, w_hh_f, w_hh_b, b_hh_f, b_hh_b, lengths, outp, Hx,
        order_b, -1);
    gemm_mfma<<<dim3(1, 256), 256, 0, stream>>>(outp, w1, b1, hmid, BB * TT, 64, 2 * HH);
    score2_kernel<<<BB * TT / 4, 256, 0, stream>>>(hmid, w2, b2, lengths, scores);
    attn_kernel<<<BB, 256, 0, stream>>>(scores, outp, temperature, lengths, seq_feat);
    head_kernel<<<BB, 256, 0, stream>>>(seq_feat, w_tens, b_tens, w_ones, b_ones, out);
  } else {
    // ---------- fallback: xg shared, two serial single-task GRU launches --
    float* xg   = (float*)ws;
    float* outp = (float*)(ws + xg_sz);
    ull*   Hx      = (ull*)(ws + xg_sz + outp_sz);
    int*   order_b = (int*)(ws + xg_sz + outp_sz + hx_sz);
    float* hmid     = xg;
    float* scores   = xg + (size_t)BB * TT * 64;
    float* seq_feat = scores + (size_t)BB * TT;

    sched_kernel<<<1, 128, 0, stream>>>(lengths, order_b);
    hipMemsetAsync(Hx, 0, hx_sz, stream);
    gemm_mfma<<<dim3(6, 256), 256, 0, stream>>>(feats, w_ih_f, b_ih_f, xg, BB * TT, G3, DD);
    gru_duo_kernel<<<256, 256, 0, stream>>>(
        xg, xg, w_hh_f, w_hh_b, b_hh_f, b_hh_b, lengths, outp, Hx,
        order_b, 0);
    hipMemsetAsync(Hx, 0, hx_sz, stream);
    gemm_mfma<<<dim3(6, 256), 256, 0, stream>>>(feats, w_ih_b, b_ih_b, xg, BB * TT, G3, DD);
    gru_duo_kernel<<<256, 256, 0, stream>>>(
        xg, xg, w_hh_f, w_hh_b, b_hh_f, b_hh_b, lengths, outp, Hx,
        order_b, 1);
    gemm_mfma<<<dim3(1, 256), 256, 0, stream>>>(outp, w1, b1, hmid, BB * TT, 64, 2 * HH);
    score2_kernel<<<BB * TT / 4, 256, 0, stream>>>(hmid, w2, b2, lengths, scores);
    attn_kernel<<<BB, 256, 0, stream>>>(scores, outp, temperature, lengths, seq_feat);
    head_kernel<<<BB, 256, 0, stream>>>(seq_feat, w_tens, b_tens, w_ones, b_ones, out);
  }
}

// Round 5
// 1826.642 us; speedup vs baseline: 1.4226x; 1.1041x over previous
//
#include <hip/hip_runtime.h>
#include <cmath>

#define BB 128
#define TT 256
#define DD 512
#define HH 256
#define G3 768   // 3*H

typedef float f32x4 __attribute__((ext_vector_type(4)));
typedef short s16x8 __attribute__((ext_vector_type(8)));
typedef unsigned long long ull;

// v_dot2_f32_f16: acc += w.f16[0]*h.f16[0] + w.f16[1]*h.f16[1]  (CDNA1+)
#define DOT2(acc, w, h) \
  asm("v_dot2_f32_f16 %0, %1, %2, %0" : "+v"(acc) : "v"(w), "v"(h))

// RNE float -> (hi bf16, lo bf16) split: x ~= hi + lo, |err| ~ 2^-17 |x|
__device__ __forceinline__ void split_bf16(float x, unsigned short& h, unsigned short& l)
{
  unsigned u = __float_as_uint(x);
  unsigned hr = u + 0x7fffu + ((u >> 16) & 1u);
  h = (unsigned short)(hr >> 16);
  float hf = __uint_as_float((unsigned)h << 16);
  float lo = x - hf;
  unsigned u2 = __float_as_uint(lo);
  unsigned lr2 = u2 + 0x7fffu + ((u2 >> 16) & 1u);
  l = (unsigned short)(lr2 >> 16);
}

// ---- MFMA split-bf16 GEMM, row-panel form ------------------------------
// C[m,n] = bias[n] + sum_k A[m,k]*W[n,k]. A (M,K) fp32, W (N,K) fp32.
// Grid (1, M/128); each block owns a 128-row panel and loops over the
// column tiles internally -> A panel is fetched from HBM ONCE (R4 had a
// grid column dimension, re-fetching A per column block: ~6x A traffic).
// Per (ct,k-chunk): stage hi/lo bf16 planes to LDS, 48 MFMAs (hh+hl+lh).
__global__ __launch_bounds__(256) void gemm_mfma(
    const float* __restrict__ A, const float* __restrict__ W,
    const float* __restrict__ bias, float* __restrict__ C,
    int M, int N, int K)
{
  __shared__ unsigned aH[128][20], aL[128][20], bH[128][20], bL[128][20];
  const int tid = threadIdx.x;
  const int row0 = blockIdx.y * 128;
  const int wid = tid >> 6, lane = tid & 63;
  const int wm = wid >> 1, wn = wid & 1;
  const int lr = lane & 15, kq = lane >> 4;
  const int sr = tid >> 1, sk = (tid & 1) * 16;   // staging: row sr, k-half sk
  const int NT = (N + 127) >> 7;

  const float* ap = A + (size_t)(row0 + sr) * K + sk;

  for (int ct = 0; ct < NT; ct++) {
    const int col0 = ct * 128;
    f32x4 acc[4][4];
#pragma unroll
    for (int i = 0; i < 4; i++)
#pragma unroll
      for (int j = 0; j < 4; j++) acc[i][j] = (f32x4){0.f, 0.f, 0.f, 0.f};

    const float* wp = W + (size_t)(col0 + sr) * K + sk;
    const bool wok = (col0 + sr) < N;
    float4 av[4], wv4[4];
#pragma unroll
    for (int i = 0; i < 4; i++) {
      av[i] = *(const float4*)(ap + 4 * i);
      wv4[i] = wok ? *(const float4*)(wp + 4 * i) : make_float4(0.f, 0.f, 0.f, 0.f);
    }

    for (int k0 = 0; k0 < K; k0 += 32) {
      __syncthreads();               // previous compute done reading LDS
#pragma unroll
      for (int i = 0; i < 4; i++) {
        const float* fa = (const float*)&av[i];
        const float* fw = (const float*)&wv4[i];
#pragma unroll
        for (int j2 = 0; j2 < 2; j2++) {
          unsigned short h0, l0, h1, l1;
          const int col = (sk >> 1) + i * 2 + j2;
          split_bf16(fa[2 * j2], h0, l0);
          split_bf16(fa[2 * j2 + 1], h1, l1);
          aH[sr][col] = (unsigned)h0 | ((unsigned)h1 << 16);
          aL[sr][col] = (unsigned)l0 | ((unsigned)l1 << 16);
          split_bf16(fw[2 * j2], h0, l0);
          split_bf16(fw[2 * j2 + 1], h1, l1);
          bH[sr][col] = (unsigned)h0 | ((unsigned)h1 << 16);
          bL[sr][col] = (unsigned)l0 | ((unsigned)l1 << 16);
        }
      }
      __syncthreads();
      if (k0 + 32 < K) {
#pragma unroll
        for (int i = 0; i < 4; i++) {
          av[i] = *(const float4*)(ap + k0 + 32 + 4 * i);
          wv4[i] = wok ? *(const float4*)(wp + k0 + 32 + 4 * i)
                       : make_float4(0.f, 0.f, 0.f, 0.f);
        }
      }
      s16x8 ah[4], al4[4], bh[4], bl4[4];
#pragma unroll
      for (int f = 0; f < 4; f++) {
        const int ra = wm * 64 + f * 16 + lr;
        const int rb = wn * 64 + f * 16 + lr;
        ah[f]  = *(const s16x8*)((const short*)&aH[ra][0] + kq * 8);
        al4[f] = *(const s16x8*)((const short*)&aL[ra][0] + kq * 8);
        bh[f]  = *(const s16x8*)((const short*)&bH[rb][0] + kq * 8);
        bl4[f] = *(const s16x8*)((const short*)&bL[rb][0] + kq * 8);
      }
#pragma unroll
      for (int mf = 0; mf < 4; mf++)
#pragma unroll
        for (int nf = 0; nf < 4; nf++) {
          acc[mf][nf] = __builtin_amdgcn_mfma_f32_16x16x32_bf16(ah[mf],  bh[nf],  acc[mf][nf], 0, 0, 0);
          acc[mf][nf] = __builtin_amdgcn_mfma_f32_16x16x32_bf16(ah[mf],  bl4[nf], acc[mf][nf], 0, 0, 0);
          acc[mf][nf] = __builtin_amdgcn_mfma_f32_16x16x32_bf16(al4[mf], bh[nf],  acc[mf][nf], 0, 0, 0);
        }
    }
    // epilogue: C/D layout col=lane&15, row=(lane>>4)*4+reg
#pragma unroll
    for (int mf = 0; mf < 4; mf++)
#pragma unroll
      for (int nf = 0; nf < 4; nf++) {
        const int c = col0 + wn * 64 + nf * 16 + lr;
        if (c < N) {
          const float bsv = bias[c];
#pragma unroll
          for (int i = 0; i < 4; i++) {
            const int r = row0 + wm * 64 + mf * 16 + kq * 4 + i;
            C[(size_t)r * N + c] = acc[mf][nf][i] + bsv;
          }
        }
      }
  }
}

// ---- weight conversion: w_hh (3H,H) f32 -> packed f16 pairs -------------
// layout wf16[dir][u][gate][kp]: thread u's 3x128 u32 are contiguous.
__global__ __launch_bounds__(256) void wcvt_kernel(
    const float* __restrict__ whh_f, const float* __restrict__ whh_b,
    unsigned* __restrict__ wf16)
{
  const int gid = blockIdx.x * 256 + threadIdx.x;
  if (gid >= 2 * 256 * 384) return;
  const int dir = gid / 98304;
  const int rem = gid % 98304;
  const int u = rem / 384;
  const int gg = (rem % 384) / 128;
  const int kp = rem % 128;
  const float* w = dir ? whh_b : whh_f;
  const float w0 = w[((size_t)gg * HH + u) * HH + 2 * kp];
  const float w1 = w[((size_t)gg * HH + u) * HH + 2 * kp + 1];
  _Float16 a = (_Float16)w0, b = (_Float16)w1;
  unsigned short ua, ub;
  __builtin_memcpy(&ua, &a, 2);
  __builtin_memcpy(&ub, &b, 2);
  wf16[gid] = (unsigned)ua | ((unsigned)ub << 16);
}

// ---- single-CU GRU: one block per (batch,dir), NO inter-block exchange --
// The R1-R4 counters proved the pair-split's cross-CU h exchange costs
// ~2-5K cy/step (agent-scope visibility crosses the non-coherent per-XCD
// L2s) vs ~900 cy of compute. This kernel removes the exchange: full-H
// recurrent weights live in THIS CU as packed-f16 pairs (3x256 f16 =
// 384 u32/lane; fits the 512-reg unified VGPR/AGPR budget at 1 wave/SIMD;
// f32 could not: 196K f32 > 131K f32 CU register capacity). Matvec via
// v_dot2_f32_f16 (4 FLOP/instr), f32 accumulate. h kept as packed f16 in
// a 1KB parity-double-buffered LDS array (uniform-address broadcast
// reads); one barrier per step; own h carried in f32 register for the
// z*h term. 256 blocks = 256 tasks, fully independent -> no spin-waits,
// no deadlock surface, makespan = longest sequence only.
__global__ __launch_bounds__(256, 1) void gru_solo_kernel(
    const float* __restrict__ xg_f, const float* __restrict__ xg_b,
    const unsigned* __restrict__ wf16,
    const float* __restrict__ bhh_f, const float* __restrict__ bhh_b,
    const int* __restrict__ lengths, float* __restrict__ outp, int mode)
{
  const int tid = threadIdx.x;
  const int bx = blockIdx.x;
  const int dir = (mode < 0) ? (bx >> 7) : mode;
  const int batch = (mode < 0) ? (bx & 127) : bx;
  const int u = tid;
  const int len = lengths[batch];
  const float* xg = dir ? xg_b : xg_f;
  const float* bhh = dir ? bhh_b : bhh_f;

  __shared__ uint4 h16[2][32];          // 256 f16 per parity
  if (tid < 32) h16[0][tid] = make_uint4(0u, 0u, 0u, 0u);

  // one-time weight load; asm barriers pin the 384 u32 in registers
  unsigned wR[128], wZ[128], wN[128];
  {
    const uint4* wb = (const uint4*)(wf16 + (size_t)(dir * 256 + u) * 384);
#pragma unroll
    for (int i = 0; i < 32; i++) {
      *(uint4*)&wR[4 * i] = wb[i];
      *(uint4*)&wZ[4 * i] = wb[32 + i];
      *(uint4*)&wN[4 * i] = wb[64 + i];
    }
#pragma unroll
    for (int i = 0; i < 128; i++) {
      asm volatile("" : "+v"(wR[i]));
      asm volatile("" : "+v"(wZ[i]));
      asm volatile("" : "+v"(wN[i]));
    }
  }
  const float br = bhh[u], bz = bhh[HH + u], bn = bhh[2 * HH + u];
  float hreg = 0.f;
  __syncthreads();

  int p = dir ? (len - 1) : 0;
  const int ps = dir ? -1 : 1;
  const float* x0 = xg + ((size_t)batch * TT + p) * G3;
  float xr = x0[u], xz = x0[HH + u], xn = x0[2 * HH + u];

  for (int t = 0; t < len; t++) {
    // prefetch next step's xg (consumed next iteration; hides HBM latency)
    float nr = 0.f, nz = 0.f, nn = 0.f;
    if (t + 1 < len) {
      const float* xq = xg + ((size_t)batch * TT + p + ps) * G3;
      nr = xq[u]; nz = xq[HH + u]; nn = xq[2 * HH + u];
    }
    float aR = 0.f, aZ = 0.f, aN = 0.f;
    const uint4* hb = h16[t & 1];
#pragma unroll
    for (int c = 0; c < 32; c++) {
      const uint4 hv = hb[c];                       // uniform-addr broadcast
      DOT2(aR, wR[4 * c + 0], hv.x); DOT2(aZ, wZ[4 * c + 0], hv.x); DOT2(aN, wN[4 * c + 0], hv.x);
      DOT2(aR, wR[4 * c + 1], hv.y); DOT2(aZ, wZ[4 * c + 1], hv.y); DOT2(aN, wN[4 * c + 1], hv.y);
      DOT2(aR, wR[4 * c + 2], hv.z); DOT2(aZ, wZ[4 * c + 2], hv.z); DOT2(aN, wN[4 * c + 2], hv.z);
      DOT2(aR, wR[4 * c + 3], hv.w); DOT2(aZ, wZ[4 * c + 3], hv.w); DOT2(aN, wN[4 * c + 3], hv.w);
    }
    const float er = __expf(-(xr + aR + br));
    const float r = __builtin_amdgcn_rcpf(1.f + er);
    const float ez = __expf(-(xz + aZ + bz));
    const float z = __builtin_amdgcn_rcpf(1.f + ez);
    const float xa = xn + r * (aN + bn);
    const float e2 = __expf(-2.f * xa);
    const float th = (1.f - e2) * __builtin_amdgcn_rcpf(1.f + e2);
    const float hn = (1.f - z) * th + z * hreg;
    hreg = hn;
    ((_Float16*)h16[(t + 1) & 1])[u] = (_Float16)hn;
    outp[((size_t)batch * TT + p) * (2 * HH) + dir * HH + u] = hn;
    __syncthreads();                   // h16[(t+1)&1] complete for next step
    p += ps; xr = nr; xz = nz; xn = nn;
  }
}

// ------------- scores from hmid: relu, dot w2, +b2; mask t>=len ----------
__global__ __launch_bounds__(256) void score2_kernel(
    const float* __restrict__ hmid, const float* __restrict__ w2,
    const float* __restrict__ b2, const int* __restrict__ lengths,
    float* __restrict__ scores)
{
  const int wv = threadIdx.x >> 6, lane = threadIdx.x & 63;
  const int bt = blockIdx.x * 4 + wv;
  const int b = bt >> 8, t = bt & 255;
  float v = 0.f;
  if (t < lengths[b]) {
    float hv = fmaxf(hmid[(size_t)bt * 64 + lane], 0.f);
    v = hv * w2[lane];
#pragma unroll
    for (int o = 32; o > 0; o >>= 1) v += __shfl_down(v, o);
    v += b2[0];
  }
  if (lane == 0) scores[bt] = v;
}

// -------- softmax + top-3 + normalize + seq_feat, 1 block per batch ------
__global__ __launch_bounds__(256) void attn_kernel(
    const float* __restrict__ scores, const float* __restrict__ outp,
    const float* __restrict__ temp_ptr, const int* __restrict__ lengths,
    float* __restrict__ seq_feat)
{
  const int b = blockIdx.x;
  const int t = threadIdx.x;
  const int len = lengths[b];
  float temp = fminf(fmaxf(temp_ptr[0], 0.001f), 10.0f);
  __shared__ float red[256];
  __shared__ int redi[256];
  __shared__ float topv[3]; __shared__ int topi[3];
  __shared__ float vn[3]; __shared__ float vsum_s;
  const bool valid = t < len;
  float logit = valid ? scores[b * TT + t] / temp : -INFINITY;
  red[t] = logit; __syncthreads();
  for (int s = 128; s > 0; s >>= 1) {
    if (t < s) red[t] = fmaxf(red[t], red[t + s]);
    __syncthreads();
  }
  float mx = red[0]; __syncthreads();
  float e = valid ? expf(logit - mx) : 0.f;
  red[t] = e; __syncthreads();
  for (int s = 128; s > 0; s >>= 1) {
    if (t < s) red[t] += red[t + s];
    __syncthreads();
  }
  float sum = red[0]; __syncthreads();
  float myp = e / sum;
  for (int it = 0; it < 3; it++) {
    red[t] = myp; redi[t] = t; __syncthreads();
    for (int s = 128; s > 0; s >>= 1) {
      if (t < s) {
        float v2 = red[t + s]; int i2 = redi[t + s];
        if (v2 > red[t] || (v2 == red[t] && i2 < redi[t])) { red[t] = v2; redi[t] = i2; }
      }
      __syncthreads();
    }
    if (t == 0) { topv[it] = red[0]; topi[it] = redi[0]; }
    __syncthreads();
    if (t == topi[it]) myp = -1.f;
    __syncthreads();
  }
  if (t == 0) {
    int k_act = len < 3 ? len : 3;
    float vsum = 0.f;
    for (int jj = 0; jj < 3; jj++) if (jj < k_act) vsum += topv[jj];
    vsum_s = vsum;
    float denom = fmaxf(vsum, 1e-8f);
    for (int jj = 0; jj < 3; jj++) vn[jj] = (jj < k_act) ? topv[jj] / denom : 0.f;
  }
  __syncthreads();
  if (vsum_s > 1e-8f) {
    for (int hh = t; hh < 2 * HH; hh += 256) {
      float s = 0.f;
      for (int jj = 0; jj < 3; jj++)
        s += vn[jj] * outp[((size_t)b * TT + topi[jj]) * (2 * HH) + hh];
      seq_feat[b * 2 * HH + hh] = s;
    }
  } else {
    float inv = 1.f / ((float)len + 1e-8f);
    for (int hh = t; hh < 2 * HH; hh += 256) {
      float s = 0.f;
      for (int tt2 = 0; tt2 < len; tt2++)
        s += outp[((size_t)b * TT + tt2) * (2 * HH) + hh];
      seq_feat[b * 2 * HH + hh] = s * inv;
    }
  }
}

// ------------------- final heads: (B,11) then (B,10) ---------------------
__global__ __launch_bounds__(256) void head_kernel(
    const float* __restrict__ seq_feat,
    const float* __restrict__ w_tens, const float* __restrict__ b_tens,
    const float* __restrict__ w_ones, const float* __restrict__ b_ones,
    float* __restrict__ d_out)
{
  const int b = blockIdx.x;
  const int lane = threadIdx.x & 63, wv = threadIdx.x >> 6;
  const float* sf = seq_feat + (size_t)b * 2 * HH;
  for (int o = wv; o < 21; o += 4) {
    const float* wr = (o < 11) ? (w_tens + (size_t)o * 2 * HH)
                               : (w_ones + (size_t)(o - 11) * 2 * HH);
    float s = 0.f;
    for (int e2 = lane; e2 < 2 * HH; e2 += 64) s += sf[e2] * wr[e2];
#pragma unroll
    for (int off2 = 32; off2 > 0; off2 >>= 1) s += __shfl_down(s, off2);
    if (lane == 0) {
      if (o < 11) d_out[b * 11 + o] = s + b_tens[o];
      else d_out[BB * 11 + b * 10 + (o - 11)] = s + b_ones[o - 11];
    }
  }
}

extern "C" void kernel_launch(void* const* d_in, const int* in_sizes, int n_in,
                              void* d_out, int out_size, void* d_ws, size_t ws_size,
                              hipStream_t stream)
{
  const float* feats       = (const float*)d_in[0];
  const int*   lengths     = (const int*)d_in[1];
  const float* temperature = (const float*)d_in[2];
  const float* w_ih_f = (const float*)d_in[3];
  const float* w_hh_f = (const float*)d_in[4];
  const float* b_ih_f = (const float*)d_in[5];
  const float* b_hh_f = (const float*)d_in[6];
  const float* w_ih_b = (const float*)d_in[7];
  const float* w_hh_b = (const float*)d_in[8];
  const float* b_ih_b = (const float*)d_in[9];
  const float* b_hh_b = (const float*)d_in[10];
  const float* w1 = (const float*)d_in[11];
  const float* b1 = (const float*)d_in[12];
  const float* w2 = (const float*)d_in[13];
  const float* b2 = (const float*)d_in[14];
  const float* w_tens = (const float*)d_in[15];
  const float* b_tens = (const float*)d_in[16];
  const float* w_ones = (const float*)d_in[17];
  const float* b_ones = (const float*)d_in[18];
  float* out = (float*)d_out;

  const size_t xg_sz   = (size_t)BB * TT * G3 * 4;        // 100.7 MB
  const size_t outp_sz = (size_t)BB * TT * 2 * HH * 4;    // 67.1 MB
  const size_t wf_sz   = (size_t)2 * 256 * 384 * 4;       // 786 KB f16 weights
  char* ws = (char*)d_ws;

  const size_t fused_need = 2 * xg_sz + outp_sz + wf_sz;

  if (ws_size >= fused_need) {
    // ---------- fused path: both xg buffers live, one solo-GRU launch ----
    float*    xg_f = (float*)ws;
    float*    xg_b = (float*)(ws + xg_sz);
    float*    outp = (float*)(ws + 2 * xg_sz);
    unsigned* wf16 = (unsigned*)(ws + 2 * xg_sz + outp_sz);
    float* hmid     = xg_f;                  // aliases (xg dead after GRU)
    float* scores   = xg_f + (size_t)BB * TT * 64;
    float* seq_feat = scores + (size_t)BB * TT;

    wcvt_kernel<<<768, 256, 0, stream>>>(w_hh_f, w_hh_b, wf16);
    gemm_mfma<<<dim3(1, 256), 256, 0, stream>>>(feats, w_ih_f, b_ih_f, xg_f, BB * TT, G3, DD);
    gemm_mfma<<<dim3(1, 256), 256, 0, stream>>>(feats, w_ih_b, b_ih_b, xg_b, BB * TT, G3, DD);
    gru_solo_kernel<<<256, 256, 0, stream>>>(
        xg_f, xg_b, wf16, b_hh_f, b_hh_b, lengths, outp, -1);
    gemm_mfma<<<dim3(1, 256), 256, 0, stream>>>(outp, w1, b1, hmid, BB * TT, 64, 2 * HH);
    score2_kernel<<<BB * TT / 4, 256, 0, stream>>>(hmid, w2, b2, lengths, scores);
    attn_kernel<<<BB, 256, 0, stream>>>(scores, outp, temperature, lengths, seq_feat);
    head_kernel<<<BB, 256, 0, stream>>>(seq_feat, w_tens, b_tens, w_ones, b_ones, out);
  } else {
    // ---------- fallback: xg shared, two serial GRU launches -------------
    float*    xg   = (float*)ws;
    float*    outp = (float*)(ws + xg_sz);
    unsigned* wf16 = (unsigned*)(ws + xg_sz + outp_sz);
    float* hmid     = xg;
    float* scores   = xg + (size_t)BB * TT * 64;
    float* seq_feat = scores + (size_t)BB * TT;

    wcvt_kernel<<<768, 256, 0, stream>>>(w_hh_f, w_hh_b, wf16);
    gemm_mfma<<<dim3(1, 256), 256, 0, stream>>>(feats, w_ih_f, b_ih_f, xg, BB * TT, G3, DD);
    gru_solo_kernel<<<BB, 256, 0, stream>>>(
        xg, xg, wf16, b_hh_f, b_hh_b, lengths, outp, 0);
    gemm_mfma<<<dim3(1, 256), 256, 0, stream>>>(feats, w_ih_b, b_ih_b, xg, BB * TT, G3, DD);
    gru_solo_kernel<<<BB, 256, 0, stream>>>(
        xg, xg, wf16, b_hh_f, b_hh_b, lengths, outp, 1);
    gemm_mfma<<<dim3(1, 256), 256, 0, stream>>>(outp, w1, b1, hmid, BB * TT, 64, 2 * HH);
    score2_kernel<<<BB * TT / 4, 256, 0, stream>>>(hmid, w2, b2, lengths, scores);
    attn_kernel<<<BB, 256, 0, stream>>>(scores, outp, temperature, lengths, seq_feat);
    head_kernel<<<BB, 256, 0, stream>>>(seq_feat, w_tens, b_tens, w_ones, b_ones, out);
  }
}

// Round 6
// 1036.481 us; speedup vs baseline: 2.5071x; 1.7624x over previous
//
#include <hip/hip_runtime.h>
#include <cmath>

#define BB 128
#define TT 256
#define DD 512
#define HH 256
#define G3 768   // 3*H

typedef float f32x4 __attribute__((ext_vector_type(4)));
typedef short s16x8 __attribute__((ext_vector_type(8)));
typedef unsigned long long ull;
typedef unsigned short u16;

// v_dot2_f32_f16: acc += w.f16[0]*h.f16[0] + w.f16[1]*h.f16[1]  (CDNA1+)
#define DOT2(acc, w, h) \
  asm("v_dot2_f32_f16 %0, %1, %2, %0" : "+v"(acc) : "v"(w), "v"(h))

// RNE float -> (hi bf16, lo bf16) split: x ~= hi + lo, |err| ~ 2^-17 |x|
__device__ __forceinline__ void split_bf16(float x, u16& h, u16& l)
{
  unsigned u = __float_as_uint(x);
  unsigned hr = u + 0x7fffu + ((u >> 16) & 1u);
  h = (u16)(hr >> 16);
  float hf = __uint_as_float((unsigned)h << 16);
  float lo = x - hf;
  unsigned u2 = __float_as_uint(lo);
  unsigned lr2 = u2 + 0x7fffu + ((u2 >> 16) & 1u);
  l = (u16)(lr2 >> 16);
}

// ---- f32 -> (hi,lo) bf16 plane conversion, 8 elems/thread ---------------
__global__ __launch_bounds__(256) void cvt_split_kernel(
    const float* __restrict__ src, u16* __restrict__ dh,
    u16* __restrict__ dl, int n8)
{
  const int i = blockIdx.x * 256 + threadIdx.x;
  if (i >= n8) return;
  const float4 v0 = *(const float4*)(src + (size_t)i * 8);
  const float4 v1 = *(const float4*)(src + (size_t)i * 8 + 4);
  float f[8] = {v0.x, v0.y, v0.z, v0.w, v1.x, v1.y, v1.z, v1.w};
  u16 hh[8], ll[8];
#pragma unroll
  for (int j = 0; j < 8; j++) split_bf16(f[j], hh[j], ll[j]);
  *(uint4*)(dh + (size_t)i * 8) = *(const uint4*)hh;
  *(uint4*)(dl + (size_t)i * 8) = *(const uint4*)ll;
}

// ---- pure-MFMA split-bf16 GEMM: C = bias + A*W^T, pre-split planes ------
// Ah/Al (M,K) bf16, Wh/Wl (N,K) bf16. Product via 3 MFMAs per fragment
// (AhWh + AhWl + AlWh), fp32 accumulate -> ~1e-5 relative error. No
// conversion VALU in the k-loop (R5's split_bf16 staging was the GEMM
// bottleneck and was recomputed per column tile). 128x128 tile, 4 waves,
// fragment mapping carried verbatim from the R4/R5 kernel (pass-verified).
__global__ __launch_bounds__(256) void gemm_bf3(
    const u16* __restrict__ Ah, const u16* __restrict__ Al,
    const u16* __restrict__ Wh, const u16* __restrict__ Wl,
    const float* __restrict__ bias, float* __restrict__ C,
    int M, int N, int K)
{
  __shared__ unsigned aH[128][20], aL[128][20], bH[128][20], bL[128][20];
  const int tid = threadIdx.x;
  const int row0 = blockIdx.y * 128, col0 = blockIdx.x * 128;
  const int wid = tid >> 6, lane = tid & 63;
  const int wm = wid >> 1, wn = wid & 1;
  const int lr = lane & 15, kq = lane >> 4;
  const int sr = tid >> 1, sh = tid & 1;     // staging: row sr, k-half sh

  f32x4 acc[4][4];
#pragma unroll
  for (int i = 0; i < 4; i++)
#pragma unroll
    for (int j = 0; j < 4; j++) acc[i][j] = (f32x4){0.f, 0.f, 0.f, 0.f};

  const u16* pah = Ah + (size_t)(row0 + sr) * K + sh * 16;
  const u16* pal = Al + (size_t)(row0 + sr) * K + sh * 16;
  const u16* pwh = Wh + (size_t)(col0 + sr) * K + sh * 16;
  const u16* pwl = Wl + (size_t)(col0 + sr) * K + sh * 16;
  const bool wok = (col0 + sr) < N;
  const uint4 z4 = make_uint4(0u, 0u, 0u, 0u);

  uint4 rah0 = *(const uint4*)(pah), rah1 = *(const uint4*)(pah + 8);
  uint4 ral0 = *(const uint4*)(pal), ral1 = *(const uint4*)(pal + 8);
  uint4 rbh0 = wok ? *(const uint4*)(pwh) : z4;
  uint4 rbh1 = wok ? *(const uint4*)(pwh + 8) : z4;
  uint4 rbl0 = wok ? *(const uint4*)(pwl) : z4;
  uint4 rbl1 = wok ? *(const uint4*)(pwl + 8) : z4;

  for (int k0 = 0; k0 < K; k0 += 32) {
    __syncthreads();               // previous compute done reading LDS
    ((uint4*)&aH[sr][sh * 8])[0] = rah0; ((uint4*)&aH[sr][sh * 8])[1] = rah1;
    ((uint4*)&aL[sr][sh * 8])[0] = ral0; ((uint4*)&aL[sr][sh * 8])[1] = ral1;
    ((uint4*)&bH[sr][sh * 8])[0] = rbh0; ((uint4*)&bH[sr][sh * 8])[1] = rbh1;
    ((uint4*)&bL[sr][sh * 8])[0] = rbl0; ((uint4*)&bL[sr][sh * 8])[1] = rbl1;
    __syncthreads();
    if (k0 + 32 < K) {             // register-prefetch next chunk
      rah0 = *(const uint4*)(pah + k0 + 32); rah1 = *(const uint4*)(pah + k0 + 40);
      ral0 = *(const uint4*)(pal + k0 + 32); ral1 = *(const uint4*)(pal + k0 + 40);
      rbh0 = wok ? *(const uint4*)(pwh + k0 + 32) : z4;
      rbh1 = wok ? *(const uint4*)(pwh + k0 + 40) : z4;
      rbl0 = wok ? *(const uint4*)(pwl + k0 + 32) : z4;
      rbl1 = wok ? *(const uint4*)(pwl + k0 + 40) : z4;
    }
    s16x8 ah[4], al4[4], bh4[4], bl4[4];
#pragma unroll
    for (int f = 0; f < 4; f++) {
      const int ra = wm * 64 + f * 16 + lr;
      const int rb = wn * 64 + f * 16 + lr;
      ah[f]  = *(const s16x8*)((const short*)&aH[ra][0] + kq * 8);
      al4[f] = *(const s16x8*)((const short*)&aL[ra][0] + kq * 8);
      bh4[f] = *(const s16x8*)((const short*)&bH[rb][0] + kq * 8);
      bl4[f] = *(const s16x8*)((const short*)&bL[rb][0] + kq * 8);
    }
#pragma unroll
    for (int mf = 0; mf < 4; mf++)
#pragma unroll
      for (int nf = 0; nf < 4; nf++) {
        acc[mf][nf] = __builtin_amdgcn_mfma_f32_16x16x32_bf16(ah[mf],  bh4[nf], acc[mf][nf], 0, 0, 0);
        acc[mf][nf] = __builtin_amdgcn_mfma_f32_16x16x32_bf16(ah[mf],  bl4[nf], acc[mf][nf], 0, 0, 0);
        acc[mf][nf] = __builtin_amdgcn_mfma_f32_16x16x32_bf16(al4[mf], bh4[nf], acc[mf][nf], 0, 0, 0);
      }
  }
  // epilogue: C/D layout col=lane&15, row=(lane>>4)*4+reg
#pragma unroll
  for (int mf = 0; mf < 4; mf++)
#pragma unroll
    for (int nf = 0; nf < 4; nf++) {
      const int c = col0 + wn * 64 + nf * 16 + lr;
      if (c < N) {
        const float bsv = bias[c];
#pragma unroll
        for (int i = 0; i < 4; i++) {
          const int r = row0 + wm * 64 + mf * 16 + kq * 4 + i;
          C[(size_t)r * N + c] = acc[mf][nf][i] + bsv;
        }
      }
    }
}

// ---- weight conversion for GRU: w_hh (3H,H) f32 -> packed f16 pairs -----
// layout: wf16[dir][thread(kc*256+u)][gate*64 + j], k = kc*128 + 2*j
__global__ __launch_bounds__(256) void wcvt_kernel(
    const float* __restrict__ whh_f, const float* __restrict__ whh_b,
    unsigned* __restrict__ wf16)
{
  const int gid = blockIdx.x * 256 + threadIdx.x;
  if (gid >= 2 * 512 * 192) return;
  const int dir = gid / (512 * 192);
  const int rem = gid % (512 * 192);
  const int th = rem / 192;
  const int q  = rem % 192;
  const int kc = th >> 8, u = th & 255;
  const int g = q / 64, j = q % 64;
  const int k = kc * 128 + 2 * j;
  const float* w = dir ? whh_b : whh_f;
  const float w0 = w[((size_t)g * HH + u) * HH + k];
  const float w1v = w[((size_t)g * HH + u) * HH + k + 1];
  _Float16 a = (_Float16)w0, b = (_Float16)w1v;
  u16 ua, ub;
  __builtin_memcpy(&ua, &a, 2);
  __builtin_memcpy(&ub, &b, 2);
  wf16[gid] = (unsigned)ua | ((unsigned)ub << 16);
}

// ---- single-CU GRU v2: 512 threads, 192 weight-VGPRs/thread -------------
// R5 failed because 384 weight u32/thread exceeded what the allocator
// would keep resident (VGPR_Count=212 proved the arrays were reloaded
// from L2 every step -> 5600cy/step, VALUBusy 10%). v2: thread (u,kc)
// owns gates r,z,n of unit u over k-slice [kc*128,kc*128+128) = 192 u32
// -> ~240 total VGPRs, inside the 256 cap that __launch_bounds__(512,2)
// sets (2 waves/SIMD also doubles latency hiding). Partial sums cross
// the kc halves via 3KB LDS; everything stays in one CU (no inter-block
// exchange -- R1-R4 proved that costs 2-5K cy/step). sched_barrier(0)
// every 4 h-broadcast reads stops the compiler batching 64 uint4 loads
// (register-pressure spike -> spill).
__global__ __launch_bounds__(512, 2) void gru_solo_kernel(
    const float* __restrict__ xg_f, const float* __restrict__ xg_b,
    const unsigned* __restrict__ wf16,
    const float* __restrict__ bhh_f, const float* __restrict__ bhh_b,
    const int* __restrict__ lengths, float* __restrict__ outp, int mode)
{
  const int tid = threadIdx.x;
  const int bx = blockIdx.x;
  const int dir = (mode < 0) ? (bx >> 7) : mode;
  const int batch = (mode < 0) ? (bx & 127) : bx;
  const int u = tid & 255, kc = tid >> 8;
  const int len = lengths[batch];
  const float* xg = dir ? xg_b : xg_f;
  const float* bhh = dir ? bhh_b : bhh_f;

  __shared__ uint4 h16[2][32];          // 256 f16 per parity
  __shared__ float part[3][256];
  if (tid < 32) h16[0][tid] = make_uint4(0u, 0u, 0u, 0u);

  // weight load: 48 uint4 = 192 u32; pinned
  unsigned wR[64], wZ[64], wN[64];
  {
    const uint4* wb = (const uint4*)(wf16 + (size_t)(dir * 512 + tid) * 192);
#pragma unroll
    for (int i = 0; i < 16; i++) {
      *(uint4*)&wR[4 * i] = wb[i];
      *(uint4*)&wZ[4 * i] = wb[16 + i];
      *(uint4*)&wN[4 * i] = wb[32 + i];
    }
#pragma unroll
    for (int i = 0; i < 64; i++)
      asm volatile("" : "+v"(wR[i]), "+v"(wZ[i]), "+v"(wN[i]));
  }
  const float br = bhh[u], bz = bhh[HH + u], bn = bhh[2 * HH + u];
  float hreg = 0.f;
  __syncthreads();

  int p = dir ? (len - 1) : 0;
  const int ps = dir ? -1 : 1;
  float xr = 0.f, xz = 0.f, xn = 0.f;
  if (kc == 0) {
    const float* x0 = xg + ((size_t)batch * TT + p) * G3;
    xr = x0[u]; xz = x0[HH + u]; xn = x0[2 * HH + u];
  }

  for (int t = 0; t < len; t++) {
    float nr = 0.f, nz = 0.f, nn = 0.f;
    if (kc == 0 && t + 1 < len) {
      const float* xq = xg + ((size_t)batch * TT + p + ps) * G3;
      nr = xq[u]; nz = xq[HH + u]; nn = xq[2 * HH + u];
    }
    float aR = 0.f, aZ = 0.f, aN = 0.f;
    const uint4* hb = &h16[t & 1][kc << 4];   // my 64-u32 k-slice
#pragma unroll
    for (int c = 0; c < 16; c++) {
      const uint4 hv = hb[c];                 // uniform-addr broadcast
      DOT2(aR, wR[4 * c + 0], hv.x); DOT2(aZ, wZ[4 * c + 0], hv.x); DOT2(aN, wN[4 * c + 0], hv.x);
      DOT2(aR, wR[4 * c + 1], hv.y); DOT2(aZ, wZ[4 * c + 1], hv.y); DOT2(aN, wN[4 * c + 1], hv.y);
      DOT2(aR, wR[4 * c + 2], hv.z); DOT2(aZ, wZ[4 * c + 2], hv.z); DOT2(aN, wN[4 * c + 2], hv.z);
      DOT2(aR, wR[4 * c + 3], hv.w); DOT2(aZ, wZ[4 * c + 3], hv.w); DOT2(aN, wN[4 * c + 3], hv.w);
      if ((c & 3) == 3) __builtin_amdgcn_sched_barrier(0);  // cap LDS-read batching
    }
    if (kc) { part[0][u] = aR; part[1][u] = aZ; part[2][u] = aN; }
    __syncthreads();
    if (!kc) {
      aR += part[0][u]; aZ += part[1][u]; aN += part[2][u];
      const float er = __expf(-(xr + aR + br));
      const float r = __builtin_amdgcn_rcpf(1.f + er);
      const float ez = __expf(-(xz + aZ + bz));
      const float z = __builtin_amdgcn_rcpf(1.f + ez);
      const float xa = xn + r * (aN + bn);
      const float e2 = __expf(-2.f * xa);
      const float th = (1.f - e2) * __builtin_amdgcn_rcpf(1.f + e2);
      const float hn = (1.f - z) * th + z * hreg;
      hreg = hn;
      ((_Float16*)h16[(t + 1) & 1])[u] = (_Float16)hn;
      outp[((size_t)batch * TT + p) * (2 * HH) + dir * HH + u] = hn;
    }
    __syncthreads();               // h16[(t+1)&1] complete for next step
    p += ps; xr = nr; xz = nz; xn = nn;
  }
}

// ------------- scores from hmid: relu, dot w2, +b2; mask t>=len ----------
__global__ __launch_bounds__(256) void score2_kernel(
    const float* __restrict__ hmid, const float* __restrict__ w2,
    const float* __restrict__ b2, const int* __restrict__ lengths,
    float* __restrict__ scores)
{
  const int wv = threadIdx.x >> 6, lane = threadIdx.x & 63;
  const int bt = blockIdx.x * 4 + wv;
  const int b = bt >> 8, t = bt & 255;
  float v = 0.f;
  if (t < lengths[b]) {
    float hv = fmaxf(hmid[(size_t)bt * 64 + lane], 0.f);
    v = hv * w2[lane];
#pragma unroll
    for (int o = 32; o > 0; o >>= 1) v += __shfl_down(v, o);
    v += b2[0];
  }
  if (lane == 0) scores[bt] = v;
}

// -------- softmax + top-3 + normalize + seq_feat, 1 block per batch ------
__global__ __launch_bounds__(256) void attn_kernel(
    const float* __restrict__ scores, const float* __restrict__ outp,
    const float* __restrict__ temp_ptr, const int* __restrict__ lengths,
    float* __restrict__ seq_feat)
{
  const int b = blockIdx.x;
  const int t = threadIdx.x;
  const int len = lengths[b];
  float temp = fminf(fmaxf(temp_ptr[0], 0.001f), 10.0f);
  __shared__ float red[256];
  __shared__ int redi[256];
  __shared__ float topv[3]; __shared__ int topi[3];
  __shared__ float vn[3]; __shared__ float vsum_s;
  const bool valid = t < len;
  float logit = valid ? scores[b * TT + t] / temp : -INFINITY;
  red[t] = logit; __syncthreads();
  for (int s = 128; s > 0; s >>= 1) {
    if (t < s) red[t] = fmaxf(red[t], red[t + s]);
    __syncthreads();
  }
  float mx = red[0]; __syncthreads();
  float e = valid ? expf(logit - mx) : 0.f;
  red[t] = e; __syncthreads();
  for (int s = 128; s > 0; s >>= 1) {
    if (t < s) red[t] += red[t + s];
    __syncthreads();
  }
  float sum = red[0]; __syncthreads();
  float myp = e / sum;
  for (int it = 0; it < 3; it++) {
    red[t] = myp; redi[t] = t; __syncthreads();
    for (int s = 128; s > 0; s >>= 1) {
      if (t < s) {
        float v2 = red[t + s]; int i2 = redi[t + s];
        if (v2 > red[t] || (v2 == red[t] && i2 < redi[t])) { red[t] = v2; redi[t] = i2; }
      }
      __syncthreads();
    }
    if (t == 0) { topv[it] = red[0]; topi[it] = redi[0]; }
    __syncthreads();
    if (t == topi[it]) myp = -1.f;
    __syncthreads();
  }
  if (t == 0) {
    int k_act = len < 3 ? len : 3;
    float vsum = 0.f;
    for (int jj = 0; jj < 3; jj++) if (jj < k_act) vsum += topv[jj];
    vsum_s = vsum;
    float denom = fmaxf(vsum, 1e-8f);
    for (int jj = 0; jj < 3; jj++) vn[jj] = (jj < k_act) ? topv[jj] / denom : 0.f;
  }
  __syncthreads();
  if (vsum_s > 1e-8f) {
    for (int hh = t; hh < 2 * HH; hh += 256) {
      float s = 0.f;
      for (int jj = 0; jj < 3; jj++)
        s += vn[jj] * outp[((size_t)b * TT + topi[jj]) * (2 * HH) + hh];
      seq_feat[b * 2 * HH + hh] = s;
    }
  } else {
    float inv = 1.f / ((float)len + 1e-8f);
    for (int hh = t; hh < 2 * HH; hh += 256) {
      float s = 0.f;
      for (int tt2 = 0; tt2 < len; tt2++)
        s += outp[((size_t)b * TT + tt2) * (2 * HH) + hh];
      seq_feat[b * 2 * HH + hh] = s * inv;
    }
  }
}

// ------------------- final heads: (B,11) then (B,10) ---------------------
__global__ __launch_bounds__(256) void head_kernel(
    const float* __restrict__ seq_feat,
    const float* __restrict__ w_tens, const float* __restrict__ b_tens,
    const float* __restrict__ w_ones, const float* __restrict__ b_ones,
    float* __restrict__ d_out)
{
  const int b = blockIdx.x;
  const int lane = threadIdx.x & 63, wv = threadIdx.x >> 6;
  const float* sf = seq_feat + (size_t)b * 2 * HH;
  for (int o = wv; o < 21; o += 4) {
    const float* wr = (o < 11) ? (w_tens + (size_t)o * 2 * HH)
                               : (w_ones + (size_t)(o - 11) * 2 * HH);
    float s = 0.f;
    for (int e2 = lane; e2 < 2 * HH; e2 += 64) s += sf[e2] * wr[e2];
#pragma unroll
    for (int off2 = 32; off2 > 0; off2 >>= 1) s += __shfl_down(s, off2);
    if (lane == 0) {
      if (o < 11) d_out[b * 11 + o] = s + b_tens[o];
      else d_out[BB * 11 + b * 10 + (o - 11)] = s + b_ones[o - 11];
    }
  }
}

extern "C" void kernel_launch(void* const* d_in, const int* in_sizes, int n_in,
                              void* d_out, int out_size, void* d_ws, size_t ws_size,
                              hipStream_t stream)
{
  const float* feats       = (const float*)d_in[0];
  const int*   lengths     = (const int*)d_in[1];
  const float* temperature = (const float*)d_in[2];
  const float* w_ih_f = (const float*)d_in[3];
  const float* w_hh_f = (const float*)d_in[4];
  const float* b_ih_f = (const float*)d_in[5];
  const float* b_hh_f = (const float*)d_in[6];
  const float* w_ih_b = (const float*)d_in[7];
  const float* w_hh_b = (const float*)d_in[8];
  const float* b_ih_b = (const float*)d_in[9];
  const float* b_hh_b = (const float*)d_in[10];
  const float* w1 = (const float*)d_in[11];
  const float* b1 = (const float*)d_in[12];
  const float* w2 = (const float*)d_in[13];
  const float* b2 = (const float*)d_in[14];
  const float* w_tens = (const float*)d_in[15];
  const float* b_tens = (const float*)d_in[16];
  const float* w_ones = (const float*)d_in[17];
  const float* b_ones = (const float*)d_in[18];
  float* out = (float*)d_out;

  const int    M       = BB * TT;                       // 32768
  const size_t xg_sz   = (size_t)M * G3 * 4;            // 100.7 MB
  const size_t outp_sz = (size_t)M * 2 * HH * 4;        // 67.1 MB
  const size_t wgru_sz = (size_t)2 * 512 * 192 * 4;     // 786 KB
  const size_t aplane  = (size_t)M * DD * 2;            // 33.55 MB (bf16 plane)
  const size_t wihpl   = (size_t)G3 * DD * 2;           // 786 KB
  const size_t w1pl    = (size_t)64 * 2 * HH * 2;       // 64 KB
  char* ws = (char*)d_ws;

  const size_t fused_need = 2 * xg_sz + outp_sz + wgru_sz + 4 * wihpl + 2 * w1pl;

  if (ws_size >= fused_need) {
    // -------- fused: A-split aliases outp (dead before GRU writes it);
    //          O-split + hmid alias xg_f (dead after GRU). --------------
    float* xg_f = (float*)ws;
    float* xg_b = (float*)(ws + xg_sz);
    float* outp = (float*)(ws + 2 * xg_sz);
    char*  wreg = ws + 2 * xg_sz + outp_sz;
    unsigned* wgru = (unsigned*)wreg;
    u16* Wfh = (u16*)(wreg + wgru_sz);
    u16* Wfl = (u16*)(wreg + wgru_sz + wihpl);
    u16* Wbh = (u16*)(wreg + wgru_sz + 2 * wihpl);
    u16* Wbl = (u16*)(wreg + wgru_sz + 3 * wihpl);
    u16* W1h = (u16*)(wreg + wgru_sz + 4 * wihpl);
    u16* W1l = (u16*)(wreg + wgru_sz + 4 * wihpl + w1pl);
    u16* Ah  = (u16*)outp;                      // alias (pre-GRU only)
    u16* Al  = (u16*)((char*)outp + aplane);
    u16* Oh  = (u16*)xg_f;                      // alias (post-GRU only)
    u16* Ol  = (u16*)((char*)xg_f + aplane);
    float* hmid     = (float*)((char*)xg_f + 2 * aplane);
    float* scores   = hmid + (size_t)M * 64;
    float* seq_feat = scores + M;

    wcvt_kernel<<<768, 256, 0, stream>>>(w_hh_f, w_hh_b, wgru);
    cvt_split_kernel<<<M * DD / 8 / 256, 256, 0, stream>>>(feats, Ah, Al, M * DD / 8);
    cvt_split_kernel<<<G3 * DD / 8 / 256, 256, 0, stream>>>(w_ih_f, Wfh, Wfl, G3 * DD / 8);
    cvt_split_kernel<<<G3 * DD / 8 / 256, 256, 0, stream>>>(w_ih_b, Wbh, Wbl, G3 * DD / 8);
    cvt_split_kernel<<<16, 256, 0, stream>>>(w1, W1h, W1l, 64 * 2 * HH / 8);
    gemm_bf3<<<dim3(6, 256), 256, 0, stream>>>(Ah, Al, Wfh, Wfl, b_ih_f, xg_f, M, G3, DD);
    gemm_bf3<<<dim3(6, 256), 256, 0, stream>>>(Ah, Al, Wbh, Wbl, b_ih_b, xg_b, M, G3, DD);
    gru_solo_kernel<<<256, 512, 0, stream>>>(
        xg_f, xg_b, wgru, b_hh_f, b_hh_b, lengths, outp, -1);
    cvt_split_kernel<<<M * 2 * HH / 8 / 256, 256, 0, stream>>>(outp, Oh, Ol, M * 2 * HH / 8);
    gemm_bf3<<<dim3(1, 256), 256, 0, stream>>>(Oh, Ol, W1h, W1l, b1, hmid, M, 64, 2 * HH);
    score2_kernel<<<M / 4, 256, 0, stream>>>(hmid, w2, b2, lengths, scores);
    attn_kernel<<<BB, 256, 0, stream>>>(scores, outp, temperature, lengths, seq_feat);
    head_kernel<<<BB, 256, 0, stream>>>(seq_feat, w_tens, b_tens, w_ones, b_ones, out);
  } else {
    // -------- fallback: single xg buffer, A-split in its own region -----
    float* xg   = (float*)ws;
    float* outp = (float*)(ws + xg_sz);
    char*  wreg = ws + xg_sz + outp_sz;
    unsigned* wgru = (unsigned*)wreg;
    u16* Wfh = (u16*)(wreg + wgru_sz);
    u16* Wfl = (u16*)(wreg + wgru_sz + wihpl);
    u16* Wbh = (u16*)(wreg + wgru_sz + 2 * wihpl);
    u16* Wbl = (u16*)(wreg + wgru_sz + 3 * wihpl);
    u16* W1h = (u16*)(wreg + wgru_sz + 4 * wihpl);
    u16* W1l = (u16*)(wreg + wgru_sz + 4 * wihpl + w1pl);
    u16* Ah  = (u16*)(wreg + wgru_sz + 4 * wihpl + 2 * w1pl);
    u16* Al  = (u16*)((char*)Ah + aplane);
    u16* Oh  = (u16*)xg;                        // alias (post-GRU only)
    u16* Ol  = (u16*)((char*)xg + aplane);
    float* hmid     = (float*)((char*)xg + 2 * aplane);
    float* scores   = hmid + (size_t)M * 64;
    float* seq_feat = scores + M;

    wcvt_kernel<<<768, 256, 0, stream>>>(w_hh_f, w_hh_b, wgru);
    cvt_split_kernel<<<M * DD / 8 / 256, 256, 0, stream>>>(feats, Ah, Al, M * DD / 8);
    cvt_split_kernel<<<G3 * DD / 8 / 256, 256, 0, stream>>>(w_ih_f, Wfh, Wfl, G3 * DD / 8);
    cvt_split_kernel<<<G3 * DD / 8 / 256, 256, 0, stream>>>(w_ih_b, Wbh, Wbl, G3 * DD / 8);
    cvt_split_kernel<<<16, 256, 0, stream>>>(w1, W1h, W1l, 64 * 2 * HH / 8);
    gemm_bf3<<<dim3(6, 256), 256, 0, stream>>>(Ah, Al, Wfh, Wfl, b_ih_f, xg, M, G3, DD);
    gru_solo_kernel<<<BB, 512, 0, stream>>>(
        xg, xg, wgru, b_hh_f, b_hh_b, lengths, outp, 0);
    gemm_bf3<<<dim3(6, 256), 256, 0, stream>>>(Ah, Al, Wbh, Wbl, b_ih_b, xg, M, G3, DD);
    gru_solo_kernel<<<BB, 512, 0, stream>>>(
        xg, xg, wgru, b_hh_f, b_hh_b, lengths, outp, 1);
    cvt_split_kernel<<<M * 2 * HH / 8 / 256, 256, 0, stream>>>(outp, Oh, Ol, M * 2 * HH / 8);
    gemm_bf3<<<dim3(1, 256), 256, 0, stream>>>(Oh, Ol, W1h, W1l, b1, hmid, M, 64, 2 * HH);
    score2_kernel<<<M / 4, 256, 0, stream>>>(hmid, w2, b2, lengths, scores);
    attn_kernel<<<BB, 256, 0, stream>>>(scores, outp, temperature, lengths, seq_feat);
    head_kernel<<<BB, 256, 0, stream>>>(seq_feat, w_tens, b_tens, w_ones, b_ones, out);
  }
}

// Round 7
// 1024.868 us; speedup vs baseline: 2.5355x; 1.0113x over previous
//
#include <hip/hip_runtime.h>
#include <cmath>

#define BB 128
#define TT 256
#define DD 512
#define HH 256
#define G3 768   // 3*H

typedef float f32x4 __attribute__((ext_vector_type(4)));
typedef short s16x8 __attribute__((ext_vector_type(8)));
typedef unsigned long long ull;
typedef unsigned short u16;

// v_dot2_f32_f16: acc += w.f16[0]*h.f16[0] + w.f16[1]*h.f16[1]  (CDNA1+)
#define DOT2(acc, w, h) \
  asm("v_dot2_f32_f16 %0, %1, %2, %0" : "+v"(acc) : "v"(w), "v"(h))

// RNE float -> (hi bf16, lo bf16) split: x ~= hi + lo, |err| ~ 2^-17 |x|
__device__ __forceinline__ void split_bf16(float x, u16& h, u16& l)
{
  unsigned u = __float_as_uint(x);
  unsigned hr = u + 0x7fffu + ((u >> 16) & 1u);
  h = (u16)(hr >> 16);
  float hf = __uint_as_float((unsigned)h << 16);
  float lo = x - hf;
  unsigned u2 = __float_as_uint(lo);
  unsigned lr2 = u2 + 0x7fffu + ((u2 >> 16) & 1u);
  l = (u16)(lr2 >> 16);
}

__device__ __forceinline__ float bf_hl(u16 h, u16 l)
{
  return __uint_as_float((unsigned)h << 16) + __uint_as_float((unsigned)l << 16);
}

// ---- f32 -> (hi,lo) bf16 plane conversion, 8 elems/thread ---------------
__global__ __launch_bounds__(256) void cvt_split_kernel(
    const float* __restrict__ src, u16* __restrict__ dh,
    u16* __restrict__ dl, int n8)
{
  const int i = blockIdx.x * 256 + threadIdx.x;
  if (i >= n8) return;
  const float4 v0 = *(const float4*)(src + (size_t)i * 8);
  const float4 v1 = *(const float4*)(src + (size_t)i * 8 + 4);
  float f[8] = {v0.x, v0.y, v0.z, v0.w, v1.x, v1.y, v1.z, v1.w};
  u16 hh[8], ll[8];
#pragma unroll
  for (int j = 0; j < 8; j++) split_bf16(f[j], hh[j], ll[j]);
  *(uint4*)(dh + (size_t)i * 8) = *(const uint4*)hh;
  *(uint4*)(dl + (size_t)i * 8) = *(const uint4*)ll;
}

// ---- pure-MFMA split-bf16 GEMM: C = bias + A*W^T, pre-split planes ------
// (unchanged from R6 -- pass-verified). 3 MFMAs per fragment (hh+hl+lh).
__global__ __launch_bounds__(256) void gemm_bf3(
    const u16* __restrict__ Ah, const u16* __restrict__ Al,
    const u16* __restrict__ Wh, const u16* __restrict__ Wl,
    const float* __restrict__ bias, float* __restrict__ C,
    int M, int N, int K)
{
  __shared__ unsigned aH[128][20], aL[128][20], bH[128][20], bL[128][20];
  const int tid = threadIdx.x;
  const int row0 = blockIdx.y * 128, col0 = blockIdx.x * 128;
  const int wid = tid >> 6, lane = tid & 63;
  const int wm = wid >> 1, wn = wid & 1;
  const int lr = lane & 15, kq = lane >> 4;
  const int sr = tid >> 1, sh = tid & 1;     // staging: row sr, k-half sh

  f32x4 acc[4][4];
#pragma unroll
  for (int i = 0; i < 4; i++)
#pragma unroll
    for (int j = 0; j < 4; j++) acc[i][j] = (f32x4){0.f, 0.f, 0.f, 0.f};

  const u16* pah = Ah + (size_t)(row0 + sr) * K + sh * 16;
  const u16* pal = Al + (size_t)(row0 + sr) * K + sh * 16;
  const u16* pwh = Wh + (size_t)(col0 + sr) * K + sh * 16;
  const u16* pwl = Wl + (size_t)(col0 + sr) * K + sh * 16;
  const bool wok = (col0 + sr) < N;
  const uint4 z4 = make_uint4(0u, 0u, 0u, 0u);

  uint4 rah0 = *(const uint4*)(pah), rah1 = *(const uint4*)(pah + 8);
  uint4 ral0 = *(const uint4*)(pal), ral1 = *(const uint4*)(pal + 8);
  uint4 rbh0 = wok ? *(const uint4*)(pwh) : z4;
  uint4 rbh1 = wok ? *(const uint4*)(pwh + 8) : z4;
  uint4 rbl0 = wok ? *(const uint4*)(pwl) : z4;
  uint4 rbl1 = wok ? *(const uint4*)(pwl + 8) : z4;

  for (int k0 = 0; k0 < K; k0 += 32) {
    __syncthreads();               // previous compute done reading LDS
    ((uint4*)&aH[sr][sh * 8])[0] = rah0; ((uint4*)&aH[sr][sh * 8])[1] = rah1;
    ((uint4*)&aL[sr][sh * 8])[0] = ral0; ((uint4*)&aL[sr][sh * 8])[1] = ral1;
    ((uint4*)&bH[sr][sh * 8])[0] = rbh0; ((uint4*)&bH[sr][sh * 8])[1] = rbh1;
    ((uint4*)&bL[sr][sh * 8])[0] = rbl0; ((uint4*)&bL[sr][sh * 8])[1] = rbl1;
    __syncthreads();
    if (k0 + 32 < K) {             // register-prefetch next chunk
      rah0 = *(const uint4*)(pah + k0 + 32); rah1 = *(const uint4*)(pah + k0 + 40);
      ral0 = *(const uint4*)(pal + k0 + 32); ral1 = *(const uint4*)(pal + k0 + 40);
      rbh0 = wok ? *(const uint4*)(pwh + k0 + 32) : z4;
      rbh1 = wok ? *(const uint4*)(pwh + k0 + 40) : z4;
      rbl0 = wok ? *(const uint4*)(pwl + k0 + 32) : z4;
      rbl1 = wok ? *(const uint4*)(pwl + k0 + 40) : z4;
    }
    s16x8 ah[4], al4[4], bh4[4], bl4[4];
#pragma unroll
    for (int f = 0; f < 4; f++) {
      const int ra = wm * 64 + f * 16 + lr;
      const int rb = wn * 64 + f * 16 + lr;
      ah[f]  = *(const s16x8*)((const short*)&aH[ra][0] + kq * 8);
      al4[f] = *(const s16x8*)((const short*)&aL[ra][0] + kq * 8);
      bh4[f] = *(const s16x8*)((const short*)&bH[rb][0] + kq * 8);
      bl4[f] = *(const s16x8*)((const short*)&bL[rb][0] + kq * 8);
    }
#pragma unroll
    for (int mf = 0; mf < 4; mf++)
#pragma unroll
      for (int nf = 0; nf < 4; nf++) {
        acc[mf][nf] = __builtin_amdgcn_mfma_f32_16x16x32_bf16(ah[mf],  bh4[nf], acc[mf][nf], 0, 0, 0);
        acc[mf][nf] = __builtin_amdgcn_mfma_f32_16x16x32_bf16(ah[mf],  bl4[nf], acc[mf][nf], 0, 0, 0);
        acc[mf][nf] = __builtin_amdgcn_mfma_f32_16x16x32_bf16(al4[mf], bh4[nf], acc[mf][nf], 0, 0, 0);
      }
  }
  // epilogue: C/D layout col=lane&15, row=(lane>>4)*4+reg
#pragma unroll
  for (int mf = 0; mf < 4; mf++)
#pragma unroll
    for (int nf = 0; nf < 4; nf++) {
      const int c = col0 + wn * 64 + nf * 16 + lr;
      if (c < N) {
        const float bsv = bias[c];
#pragma unroll
        for (int i = 0; i < 4; i++) {
          const int r = row0 + wm * 64 + mf * 16 + kq * 4 + i;
          C[(size_t)r * N + c] = acc[mf][nf][i] + bsv;
        }
      }
    }
}

// ---- weight conversion for GRU: w_hh (3H,H) f32 -> packed f16 pairs -----
// layout: wf16[dir][thread(kc*256+u)][gate*64 + j], k = kc*128 + 2*j
__global__ __launch_bounds__(256) void wcvt_kernel(
    const float* __restrict__ whh_f, const float* __restrict__ whh_b,
    unsigned* __restrict__ wf16)
{
  const int gid = blockIdx.x * 256 + threadIdx.x;
  if (gid >= 2 * 512 * 192) return;
  const int dir = gid / (512 * 192);
  const int rem = gid % (512 * 192);
  const int th = rem / 192;
  const int q  = rem % 192;
  const int kc = th >> 8, u = th & 255;
  const int g = q / 64, j = q % 64;
  const int k = kc * 128 + 2 * j;
  const float* w = dir ? whh_b : whh_f;
  const float w0 = w[((size_t)g * HH + u) * HH + k];
  const float w1v = w[((size_t)g * HH + u) * HH + k + 1];
  _Float16 a = (_Float16)w0, b = (_Float16)w1v;
  u16 ua, ub;
  __builtin_memcpy(&ua, &a, 2);
  __builtin_memcpy(&ub, &b, 2);
  wf16[gid] = (unsigned)ua | ((unsigned)ub << 16);
}

// ---- single-CU GRU v3: SROA-safe uint4 weight arrays --------------------
// R6's VGPR_Count=116 (<< the 192 weight u32/thread) exposed the leak:
// `unsigned wR[128]` filled via type-punned `*(uint4*)&wR[4i]=...` stores
// defeats SROA -> the array lives in SCRATCH and every DOT2 operand is a
// scratch reload (~3070cy/step vs 768cy issue floor). R1's float4-array
// pattern (direct vector loads, component consumption, static indices)
// WAS register-resident (VGPR=256). v3 restores that shape: uint4 wR[16]
// loaded directly, pinned per-component, consumed as .x/.y/.z/.w with
// compile-time indices. Also fuses the outp bf16 hi/lo split into the
// epilogue (kills the 134MB cvt_split(outp) pass); attn reconstructs
// f32 = hi+lo. Structure otherwise R6: 512 thr, thread (u,kc) owns gates
// r,z,n of unit u over k-slice [kc*128,+128); LDS partial-sum cross;
// 2 barriers/step; no inter-block anything.
__global__ __launch_bounds__(512, 2) void gru_solo_kernel(
    const float* __restrict__ xg_f, const float* __restrict__ xg_b,
    const unsigned* __restrict__ wf16,
    const float* __restrict__ bhh_f, const float* __restrict__ bhh_b,
    const int* __restrict__ lengths,
    u16* __restrict__ Oh, u16* __restrict__ Ol, int mode)
{
  const int tid = threadIdx.x;
  const int bx = blockIdx.x;
  const int dir = (mode < 0) ? (bx >> 7) : mode;
  const int batch = (mode < 0) ? (bx & 127) : bx;
  const int u = tid & 255, kc = tid >> 8;
  const int len = lengths[batch];
  const float* xg = dir ? xg_b : xg_f;
  const float* bhh = dir ? bhh_b : bhh_f;

  __shared__ uint4 h16[2][32];          // 256 f16 per parity
  __shared__ float part[3][256];
  if (tid < 32) h16[0][tid] = make_uint4(0u, 0u, 0u, 0u);

  // weight load: 48 uint4 = 192 u32, SROA-friendly (no punned stores)
  uint4 wR[16], wZ[16], wN[16];
  {
    const uint4* wb = (const uint4*)(wf16 + (size_t)(dir * 512 + tid) * 192);
#pragma unroll
    for (int i = 0; i < 16; i++) wR[i] = wb[i];
#pragma unroll
    for (int i = 0; i < 16; i++) wZ[i] = wb[16 + i];
#pragma unroll
    for (int i = 0; i < 16; i++) wN[i] = wb[32 + i];
#pragma unroll
    for (int i = 0; i < 16; i++) {
      asm volatile("" : "+v"(wR[i].x), "+v"(wR[i].y), "+v"(wR[i].z), "+v"(wR[i].w));
      asm volatile("" : "+v"(wZ[i].x), "+v"(wZ[i].y), "+v"(wZ[i].z), "+v"(wZ[i].w));
      asm volatile("" : "+v"(wN[i].x), "+v"(wN[i].y), "+v"(wN[i].z), "+v"(wN[i].w));
    }
  }
  const float br = bhh[u], bz = bhh[HH + u], bn = bhh[2 * HH + u];
  float hreg = 0.f;
  __syncthreads();

  int p = dir ? (len - 1) : 0;
  const int ps = dir ? -1 : 1;
  float xr = 0.f, xz = 0.f, xn = 0.f;
  if (kc == 0) {
    const float* x0 = xg + ((size_t)batch * TT + p) * G3;
    xr = x0[u]; xz = x0[HH + u]; xn = x0[2 * HH + u];
  }

  for (int t = 0; t < len; t++) {
    float nr = 0.f, nz = 0.f, nn = 0.f;
    if (kc == 0 && t + 1 < len) {
      const float* xq = xg + ((size_t)batch * TT + p + ps) * G3;
      nr = xq[u]; nz = xq[HH + u]; nn = xq[2 * HH + u];
    }
    float aR = 0.f, aZ = 0.f, aN = 0.f;
    const uint4* hb = &h16[t & 1][kc << 4];   // my 16-uint4 k-slice
#pragma unroll
    for (int c = 0; c < 16; c++) {
      const uint4 hv = hb[c];                 // uniform-addr broadcast
      DOT2(aR, wR[c].x, hv.x); DOT2(aZ, wZ[c].x, hv.x); DOT2(aN, wN[c].x, hv.x);
      DOT2(aR, wR[c].y, hv.y); DOT2(aZ, wZ[c].y, hv.y); DOT2(aN, wN[c].y, hv.y);
      DOT2(aR, wR[c].z, hv.z); DOT2(aZ, wZ[c].z, hv.z); DOT2(aN, wN[c].z, hv.z);
      DOT2(aR, wR[c].w, hv.w); DOT2(aZ, wZ[c].w, hv.w); DOT2(aN, wN[c].w, hv.w);
      if ((c & 3) == 3) __builtin_amdgcn_sched_barrier(0);  // cap LDS batching
    }
    if (kc) { part[0][u] = aR; part[1][u] = aZ; part[2][u] = aN; }
    __syncthreads();
    if (!kc) {
      aR += part[0][u]; aZ += part[1][u]; aN += part[2][u];
      const float er = __expf(-(xr + aR + br));
      const float r = __builtin_amdgcn_rcpf(1.f + er);
      const float ez = __expf(-(xz + aZ + bz));
      const float z = __builtin_amdgcn_rcpf(1.f + ez);
      const float xa = xn + r * (aN + bn);
      const float e2 = __expf(-2.f * xa);
      const float th = (1.f - e2) * __builtin_amdgcn_rcpf(1.f + e2);
      const float hn = (1.f - z) * th + z * hreg;
      hreg = hn;
      ((_Float16*)h16[(t + 1) & 1])[u] = (_Float16)hn;
      u16 oh, ol;
      split_bf16(hn, oh, ol);
      const size_t oi = ((size_t)batch * TT + p) * (2 * HH) + dir * HH + u;
      Oh[oi] = oh; Ol[oi] = ol;
    }
    __syncthreads();               // h16[(t+1)&1] complete for next step
    p += ps; xr = nr; xz = nz; xn = nn;
  }
}

// ------------- scores from hmid: relu, dot w2, +b2; mask t>=len ----------
__global__ __launch_bounds__(256) void score2_kernel(
    const float* __restrict__ hmid, const float* __restrict__ w2,
    const float* __restrict__ b2, const int* __restrict__ lengths,
    float* __restrict__ scores)
{
  const int wv = threadIdx.x >> 6, lane = threadIdx.x & 63;
  const int bt = blockIdx.x * 4 + wv;
  const int b = bt >> 8, t = bt & 255;
  float v = 0.f;
  if (t < lengths[b]) {
    float hv = fmaxf(hmid[(size_t)bt * 64 + lane], 0.f);
    v = hv * w2[lane];
#pragma unroll
    for (int o = 32; o > 0; o >>= 1) v += __shfl_down(v, o);
    v += b2[0];
  }
  if (lane == 0) scores[bt] = v;
}

// -------- softmax + top-3 + normalize + seq_feat, 1 block per batch ------
// outp now lives as bf16 hi/lo planes; f32 value = hi + lo (exact to 1e-5)
__global__ __launch_bounds__(256) void attn_kernel(
    const float* __restrict__ scores,
    const u16* __restrict__ Oh, const u16* __restrict__ Ol,
    const float* __restrict__ temp_ptr, const int* __restrict__ lengths,
    float* __restrict__ seq_feat)
{
  const int b = blockIdx.x;
  const int t = threadIdx.x;
  const int len = lengths[b];
  float temp = fminf(fmaxf(temp_ptr[0], 0.001f), 10.0f);
  __shared__ float red[256];
  __shared__ int redi[256];
  __shared__ float topv[3]; __shared__ int topi[3];
  __shared__ float vn[3]; __shared__ float vsum_s;
  const bool valid = t < len;
  float logit = valid ? scores[b * TT + t] / temp : -INFINITY;
  red[t] = logit; __syncthreads();
  for (int s = 128; s > 0; s >>= 1) {
    if (t < s) red[t] = fmaxf(red[t], red[t + s]);
    __syncthreads();
  }
  float mx = red[0]; __syncthreads();
  float e = valid ? expf(logit - mx) : 0.f;
  red[t] = e; __syncthreads();
  for (int s = 128; s > 0; s >>= 1) {
    if (t < s) red[t] += red[t + s];
    __syncthreads();
  }
  float sum = red[0]; __syncthreads();
  float myp = e / sum;
  for (int it = 0; it < 3; it++) {
    red[t] = myp; redi[t] = t; __syncthreads();
    for (int s = 128; s > 0; s >>= 1) {
      if (t < s) {
        float v2 = red[t + s]; int i2 = redi[t + s];
        if (v2 > red[t] || (v2 == red[t] && i2 < redi[t])) { red[t] = v2; redi[t] = i2; }
      }
      __syncthreads();
    }
    if (t == 0) { topv[it] = red[0]; topi[it] = redi[0]; }
    __syncthreads();
    if (t == topi[it]) myp = -1.f;
    __syncthreads();
  }
  if (t == 0) {
    int k_act = len < 3 ? len : 3;
    float vsum = 0.f;
    for (int jj = 0; jj < 3; jj++) if (jj < k_act) vsum += topv[jj];
    vsum_s = vsum;
    float denom = fmaxf(vsum, 1e-8f);
    for (int jj = 0; jj < 3; jj++) vn[jj] = (jj < k_act) ? topv[jj] / denom : 0.f;
  }
  __syncthreads();
  if (vsum_s > 1e-8f) {
    for (int hh = t; hh < 2 * HH; hh += 256) {
      float s = 0.f;
      for (int jj = 0; jj < 3; jj++) {
        const size_t oi = ((size_t)b * TT + topi[jj]) * (2 * HH) + hh;
        s += vn[jj] * bf_hl(Oh[oi], Ol[oi]);
      }
      seq_feat[b * 2 * HH + hh] = s;
    }
  } else {
    float inv = 1.f / ((float)len + 1e-8f);
    for (int hh = t; hh < 2 * HH; hh += 256) {
      float s = 0.f;
      for (int tt2 = 0; tt2 < len; tt2++) {
        const size_t oi = ((size_t)b * TT + tt2) * (2 * HH) + hh;
        s += bf_hl(Oh[oi], Ol[oi]);
      }
      seq_feat[b * 2 * HH + hh] = s * inv;
    }
  }
}

// ------------------- final heads: (B,11) then (B,10) ---------------------
__global__ __launch_bounds__(256) void head_kernel(
    const float* __restrict__ seq_feat,
    const float* __restrict__ w_tens, const float* __restrict__ b_tens,
    const float* __restrict__ w_ones, const float* __restrict__ b_ones,
    float* __restrict__ d_out)
{
  const int b = blockIdx.x;
  const int lane = threadIdx.x & 63, wv = threadIdx.x >> 6;
  const float* sf = seq_feat + (size_t)b * 2 * HH;
  for (int o = wv; o < 21; o += 4) {
    const float* wr = (o < 11) ? (w_tens + (size_t)o * 2 * HH)
                               : (w_ones + (size_t)(o - 11) * 2 * HH);
    float s = 0.f;
    for (int e2 = lane; e2 < 2 * HH; e2 += 64) s += sf[e2] * wr[e2];
#pragma unroll
    for (int off2 = 32; off2 > 0; off2 >>= 1) s += __shfl_down(s, off2);
    if (lane == 0) {
      if (o < 11) d_out[b * 11 + o] = s + b_tens[o];
      else d_out[BB * 11 + b * 10 + (o - 11)] = s + b_ones[o - 11];
    }
  }
}

extern "C" void kernel_launch(void* const* d_in, const int* in_sizes, int n_in,
                              void* d_out, int out_size, void* d_ws, size_t ws_size,
                              hipStream_t stream)
{
  const float* feats       = (const float*)d_in[0];
  const int*   lengths     = (const int*)d_in[1];
  const float* temperature = (const float*)d_in[2];
  const float* w_ih_f = (const float*)d_in[3];
  const float* w_hh_f = (const float*)d_in[4];
  const float* b_ih_f = (const float*)d_in[5];
  const float* b_hh_f = (const float*)d_in[6];
  const float* w_ih_b = (const float*)d_in[7];
  const float* w_hh_b = (const float*)d_in[8];
  const float* b_ih_b = (const float*)d_in[9];
  const float* b_hh_b = (const float*)d_in[10];
  const float* w1 = (const float*)d_in[11];
  const float* b1 = (const float*)d_in[12];
  const float* w2 = (const float*)d_in[13];
  const float* b2 = (const float*)d_in[14];
  const float* w_tens = (const float*)d_in[15];
  const float* b_tens = (const float*)d_in[16];
  const float* w_ones = (const float*)d_in[17];
  const float* b_ones = (const float*)d_in[18];
  float* out = (float*)d_out;

  const int    M       = BB * TT;                       // 32768
  const size_t xg_sz   = (size_t)M * G3 * 4;            // 100.7 MB
  const size_t opl_sz  = (size_t)M * 2 * HH * 2;        // 33.55 MB (one O plane)
  const size_t wgru_sz = (size_t)2 * 512 * 192 * 4;     // 786 KB
  const size_t aplane  = (size_t)M * DD * 2;            // 33.55 MB (bf16 A plane)
  const size_t wihpl   = (size_t)G3 * DD * 2;           // 786 KB
  const size_t w1pl    = (size_t)64 * 2 * HH * 2;       // 64 KB
  char* ws = (char*)d_ws;

  const size_t fused_need = 2 * xg_sz + 2 * opl_sz + wgru_sz + 4 * wihpl + 2 * w1pl;

  if (ws_size >= fused_need) {
    // -------- fused: A-split aliases the O-plane region (dead before GRU
    //          writes it); hmid/scores/seq_feat alias xg_f (dead after GRU).
    float* xg_f = (float*)ws;
    float* xg_b = (float*)(ws + xg_sz);
    u16*   Oh   = (u16*)(ws + 2 * xg_sz);
    u16*   Ol   = (u16*)(ws + 2 * xg_sz + opl_sz);
    char*  wreg = ws + 2 * xg_sz + 2 * opl_sz;
    unsigned* wgru = (unsigned*)wreg;
    u16* Wfh = (u16*)(wreg + wgru_sz);
    u16* Wfl = (u16*)(wreg + wgru_sz + wihpl);
    u16* Wbh = (u16*)(wreg + wgru_sz + 2 * wihpl);
    u16* Wbl = (u16*)(wreg + wgru_sz + 3 * wihpl);
    u16* W1h = (u16*)(wreg + wgru_sz + 4 * wihpl);
    u16* W1l = (u16*)(wreg + wgru_sz + 4 * wihpl + w1pl);
    u16* Ah  = (u16*)Oh;                        // alias (pre-GRU only)
    u16* Al  = (u16*)((char*)Oh + aplane);
    float* hmid     = xg_f;                     // alias (post-GRU only)
    float* scores   = hmid + (size_t)M * 64;
    float* seq_feat = scores + M;

    wcvt_kernel<<<768, 256, 0, stream>>>(w_hh_f, w_hh_b, wgru);
    cvt_split_kernel<<<M * DD / 8 / 256, 256, 0, stream>>>(feats, Ah, Al, M * DD / 8);
    cvt_split_kernel<<<G3 * DD / 8 / 256, 256, 0, stream>>>(w_ih_f, Wfh, Wfl, G3 * DD / 8);
    cvt_split_kernel<<<G3 * DD / 8 / 256, 256, 0, stream>>>(w_ih_b, Wbh, Wbl, G3 * DD / 8);
    cvt_split_kernel<<<16, 256, 0, stream>>>(w1, W1h, W1l, 64 * 2 * HH / 8);
    gemm_bf3<<<dim3(6, 256), 256, 0, stream>>>(Ah, Al, Wfh, Wfl, b_ih_f, xg_f, M, G3, DD);
    gemm_bf3<<<dim3(6, 256), 256, 0, stream>>>(Ah, Al, Wbh, Wbl, b_ih_b, xg_b, M, G3, DD);
    gru_solo_kernel<<<256, 512, 0, stream>>>(
        xg_f, xg_b, wgru, b_hh_f, b_hh_b, lengths, Oh, Ol, -1);
    gemm_bf3<<<dim3(1, 256), 256, 0, stream>>>(Oh, Ol, W1h, W1l, b1, hmid, M, 64, 2 * HH);
    score2_kernel<<<M / 4, 256, 0, stream>>>(hmid, w2, b2, lengths, scores);
    attn_kernel<<<BB, 256, 0, stream>>>(scores, Oh, Ol, temperature, lengths, seq_feat);
    head_kernel<<<BB, 256, 0, stream>>>(seq_feat, w_tens, b_tens, w_ones, b_ones, out);
  } else {
    // -------- fallback: single xg buffer; A-split in its own region -----
    float* xg   = (float*)ws;
    u16*   Oh   = (u16*)(ws + xg_sz);
    u16*   Ol   = (u16*)(ws + xg_sz + opl_sz);
    char*  wreg = ws + xg_sz + 2 * opl_sz;
    unsigned* wgru = (unsigned*)wreg;
    u16* Wfh = (u16*)(wreg + wgru_sz);
    u16* Wfl = (u16*)(wreg + wgru_sz + wihpl);
    u16* Wbh = (u16*)(wreg + wgru_sz + 2 * wihpl);
    u16* Wbl = (u16*)(wreg + wgru_sz + 3 * wihpl);
    u16* W1h = (u16*)(wreg + wgru_sz + 4 * wihpl);
    u16* W1l = (u16*)(wreg + wgru_sz + 4 * wihpl + w1pl);
    u16* Ah  = (u16*)(wreg + wgru_sz + 4 * wihpl + 2 * w1pl);
    u16* Al  = (u16*)((char*)Ah + aplane);
    float* hmid     = xg;                       // alias (post-GRU only)
    float* scores   = hmid + (size_t)M * 64;
    float* seq_feat = scores + M;

    wcvt_kernel<<<768, 256, 0, stream>>>(w_hh_f, w_hh_b, wgru);
    cvt_split_kernel<<<M * DD / 8 / 256, 256, 0, stream>>>(feats, Ah, Al, M * DD / 8);
    cvt_split_kernel<<<G3 * DD / 8 / 256, 256, 0, stream>>>(w_ih_f, Wfh, Wfl, G3 * DD / 8);
    cvt_split_kernel<<<G3 * DD / 8 / 256, 256, 0, stream>>>(w_ih_b, Wbh, Wbl, G3 * DD / 8);
    cvt_split_kernel<<<16, 256, 0, stream>>>(w1, W1h, W1l, 64 * 2 * HH / 8);
    gemm_bf3<<<dim3(6, 256), 256, 0, stream>>>(Ah, Al, Wfh, Wfl, b_ih_f, xg, M, G3, DD);
    gru_solo_kernel<<<BB, 512, 0, stream>>>(
        xg, xg, wgru, b_hh_f, b_hh_b, lengths, Oh, Ol, 0);
    gemm_bf3<<<dim3(6, 256), 256, 0, stream>>>(Ah, Al, Wbh, Wbl, b_ih_b, xg, M, G3, DD);
    gru_solo_kernel<<<BB, 512, 0, stream>>>(
        xg, xg, wgru, b_hh_f, b_hh_b, lengths, Oh, Ol, 1);
    gemm_bf3<<<dim3(1, 256), 256, 0, stream>>>(Oh, Ol, W1h, W1l, b1, hmid, M, 64, 2 * HH);
    score2_kernel<<<M / 4, 256, 0, stream>>>(hmid, w2, b2, lengths, scores);
    attn_kernel<<<BB, 256, 0, stream>>>(scores, Oh, Ol, temperature, lengths, seq_feat);
    head_kernel<<<BB, 256, 0, stream>>>(seq_feat, w_tens, b_tens, w_ones, b_ones, out);
  }
}